// Round 12
// baseline (232.324 us; speedup 1.0000x reference)
//
#include <hip/hip_runtime.h>
#include <math.h>

#define EPSF 1e-6f

typedef __attribute__((ext_vector_type(8))) short short8v;
typedef __attribute__((ext_vector_type(8))) unsigned short u16x8;
typedef __attribute__((ext_vector_type(4))) float f32x4;
typedef __attribute__((ext_vector_type(4))) unsigned short u16x4;

__device__ __forceinline__ unsigned short f2bf(float f) {
    union { float f; unsigned u; } v; v.f = f;
    return (unsigned short)((v.u + 0x7FFFu + ((v.u >> 16) & 1u)) >> 16);
}
// XOR swizzle for [row][128-ushort] LDS tiles (16B granularity)
__device__ __forceinline__ int swe(int row, int k) {
    return (row << 7) + (k ^ ((row & 7) << 3));
}
// XOR swizzle for [row][64-ushort] LDS tiles (rows accessed stride-1)
__device__ __forceinline__ int swe64(int row, int k) {
    return (row << 6) + (k ^ ((row & 7) << 3));
}
// W-tile swizzle for [n][64-ushort]: granule ^= (n + (n>>2)) & 7.
// Bank-enumerated: stride-4-n b128 writes AND stride-1-n b128 reads both
// spread over all 32 banks (<=2-way).
__device__ __forceinline__ int swn(int n, int k) {
    return (n << 6) + (k & 7) +
           ((((k >> 3) & 7) ^ ((n + (n >> 2)) & 7)) << 3);
}

// ================= little_encode via MFMA (unchanged, verified) =============
__global__ __launch_bounds__(256) void k_little_encode_mfma(
    const float* __restrict__ x,
    const float* __restrict__ noise,
    const float* __restrict__ w1,
    const float* __restrict__ b1,
    const float* __restrict__ w2,
    const float* __restrict__ b2,
    float* __restrict__ nli,
    unsigned short* __restrict__ nli_bf)
{
    __shared__ __align__(16) unsigned short pS[128 * 128];
    __shared__ __align__(16) unsigned short w1S[128 * 128];
    __shared__ __align__(16) unsigned short hS[128 * 128];
    __shared__ __align__(16) unsigned short w2S[32 * 128];
    __shared__ float b1S[128];
    __shared__ float b2S[32];
    __shared__ float sums[128][4];

    int t = threadIdx.x;

    {
        uint4 z4 = make_uint4(0, 0, 0, 0);
        #pragma unroll
        for (int i = 0; i < 8; ++i) {
            *(uint4*)&pS[(i * 256 + t) * 8]  = z4;
            *(uint4*)&w1S[(i * 256 + t) * 8] = z4;
        }
    }
    __syncthreads();

    for (int k = (t >> 4); k < 75; k += 16) {
        int n0 = (t & 15) * 8;
        float4 a0 = *(const float4*)(w1 + k * 128 + n0);
        float4 a1 = *(const float4*)(w1 + k * 128 + n0 + 4);
        w1S[swe(n0 + 0, k)] = f2bf(a0.x);
        w1S[swe(n0 + 1, k)] = f2bf(a0.y);
        w1S[swe(n0 + 2, k)] = f2bf(a0.z);
        w1S[swe(n0 + 3, k)] = f2bf(a0.w);
        w1S[swe(n0 + 4, k)] = f2bf(a1.x);
        w1S[swe(n0 + 5, k)] = f2bf(a1.y);
        w1S[swe(n0 + 6, k)] = f2bf(a1.z);
        w1S[swe(n0 + 7, k)] = f2bf(a1.w);
    }
    for (int k = (t >> 3); k < 128; k += 32) {
        int n0 = (t & 7) * 4;
        float4 a = *(const float4*)(w2 + k * 32 + n0);
        w2S[swe(n0 + 0, k)] = f2bf(a.x);
        w2S[swe(n0 + 1, k)] = f2bf(a.y);
        w2S[swe(n0 + 2, k)] = f2bf(a.z);
        w2S[swe(n0 + 3, k)] = f2bf(a.w);
    }
    if (t < 128) b1S[t] = b1[t];
    if (t < 32)  b2S[t] = b2[t];

    int row  = t & 127;
    int half = t >> 7;
    int R0 = blockIdx.x * 128 + row;
    int bb = R0 / 441;
    int p  = R0 - bb * 441;
    int pi = p / 21, pj = p - pi * 21;
    const float* xb = x + (size_t)bb * 3 * 63 * 63;

    float v[38];
    {
        float sA = 0.f, sB = 0.f;
        if (half == 0) {
            #pragma unroll
            for (int i = 0; i < 38; ++i) {
                const int k = i;
                const int c = k / 25, o = k % 25, ph = o / 5, pw = o % 5;
                int y = pi * 3 + ph - 1, xx = pj * 3 + pw - 1;
                float val = 0.f;
                if ((unsigned)y < 63u && (unsigned)xx < 63u)
                    val = xb[(c * 63 + y) * 63 + xx];
                v[i] = val;
                if (k < 25) sA += val; else sB += val;
            }
        } else {
            #pragma unroll
            for (int i = 0; i < 37; ++i) {
                const int k = 38 + i;
                const int c = k / 25, o = k % 25, ph = o / 5, pw = o % 5;
                int y = pi * 3 + ph - 1, xx = pj * 3 + pw - 1;
                float val = 0.f;
                if ((unsigned)y < 63u && (unsigned)xx < 63u)
                    val = xb[(c * 63 + y) * 63 + xx];
                v[i] = val;
                if (k < 50) sA += val; else sB += val;
            }
        }
        sums[row][half * 2 + 0] = sA;
        sums[row][half * 2 + 1] = sB;
    }
    __syncthreads();
    {
        float c0 = sums[row][0];
        float c1 = sums[row][1] + sums[row][2];
        float c2 = sums[row][3];
        if (half == 0) {
            #pragma unroll
            for (int i = 0; i < 38; ++i) {
                const int k = i;
                float cs = (k < 25) ? c0 : c1;
                pS[swe(row, k)] = f2bf(v[i] + EPSF * cs);
            }
        } else {
            #pragma unroll
            for (int i = 0; i < 37; ++i) {
                const int k = 38 + i;
                float cs = (k < 50) ? c1 : c2;
                pS[swe(row, k)] = f2bf(v[i] + EPSF * cs);
            }
        }
    }
    __syncthreads();

    int w = t >> 6, lane = t & 63, lr = lane & 15, lg = lane >> 4;

    f32x4 acc[2][8];
    #pragma unroll
    for (int mi = 0; mi < 2; ++mi)
        #pragma unroll
        for (int ni = 0; ni < 8; ++ni)
            acc[mi][ni] = (f32x4){0.f, 0.f, 0.f, 0.f};

    #pragma unroll
    for (int ks = 0; ks < 3; ++ks) {
        int kb = ks * 32 + lg * 8;
        short8v a0 = *(const short8v*)&pS[swe(w * 32 + lr, kb)];
        short8v a1 = *(const short8v*)&pS[swe(w * 32 + 16 + lr, kb)];
        #pragma unroll
        for (int ni = 0; ni < 8; ++ni) {
            short8v bf = *(const short8v*)&w1S[swe(ni * 16 + lr, kb)];
            acc[0][ni] = __builtin_amdgcn_mfma_f32_16x16x32_bf16(a0, bf, acc[0][ni], 0, 0, 0);
            acc[1][ni] = __builtin_amdgcn_mfma_f32_16x16x32_bf16(a1, bf, acc[1][ni], 0, 0, 0);
        }
    }
    #pragma unroll
    for (int mi = 0; mi < 2; ++mi)
        #pragma unroll
        for (int ni = 0; ni < 8; ++ni) {
            int n = ni * 16 + lr;
            float bv = b1S[n];
            #pragma unroll
            for (int r = 0; r < 4; ++r) {
                int m = w * 32 + mi * 16 + lg * 4 + r;
                hS[swe(m, n)] = f2bf(fmaxf(acc[mi][ni][r] + bv, 0.f));
            }
        }

    f32x4 acc2[2][2];
    #pragma unroll
    for (int mi = 0; mi < 2; ++mi)
        #pragma unroll
        for (int ni = 0; ni < 2; ++ni)
            acc2[mi][ni] = (f32x4){0.f, 0.f, 0.f, 0.f};

    #pragma unroll
    for (int kh = 0; kh < 4; ++kh) {
        int kb = kh * 32 + lg * 8;
        short8v a0 = *(const short8v*)&hS[swe(w * 32 + lr, kb)];
        short8v a1 = *(const short8v*)&hS[swe(w * 32 + 16 + lr, kb)];
        #pragma unroll
        for (int ni = 0; ni < 2; ++ni) {
            short8v bf = *(const short8v*)&w2S[swe(ni * 16 + lr, kb)];
            acc2[0][ni] = __builtin_amdgcn_mfma_f32_16x16x32_bf16(a0, bf, acc2[0][ni], 0, 0, 0);
            acc2[1][ni] = __builtin_amdgcn_mfma_f32_16x16x32_bf16(a1, bf, acc2[1][ni], 0, 0, 0);
        }
    }

    #pragma unroll
    for (int mi = 0; mi < 2; ++mi)
        #pragma unroll
        for (int r = 0; r < 4; ++r) {
            int m = w * 32 + mi * 16 + lg * 4 + r;
            size_t R = (size_t)blockIdx.x * 128 + m;
            float mean = acc2[mi][0][r] + b2S[lr];
            float lv   = acc2[mi][1][r] + b2S[16 + lr];
            float z = noise[R * 16 + lr] * expf(0.5f * lv) + mean;
            nli[R * 16 + lr] = z;
            nli_bf[R * 16 + lr] = f2bf(z);
        }
}

// ================= little_decode via MFMA (unchanged, verified) =============
__global__ __launch_bounds__(256) void k_little_decode_mfma(
    const float* __restrict__ latent,
    const float* __restrict__ w1,
    const float* __restrict__ b1,
    const float* __restrict__ w2,
    const float* __restrict__ b2,
    float* __restrict__ img)
{
    __shared__ __align__(16) unsigned short w1S[128 * 64];
    __shared__ __align__(16) unsigned short hS[128 * 128];
    __shared__ __align__(16) unsigned short w2S[80 * 128];
    __shared__ float b1S[128];
    __shared__ float b2S[80];

    int t = threadIdx.x;

    {
        uint4 z4 = make_uint4(0, 0, 0, 0);
        #pragma unroll
        for (int i = 0; i < 4; ++i)
            *(uint4*)&w1S[(i * 256 + t) * 8] = z4;
        #pragma unroll
        for (int i = 0; i < 5; ++i)
            *(uint4*)&w2S[(i * 256 + t) * 8] = z4;
    }
    __syncthreads();

    {
        int k = t >> 4;
        int n0 = (t & 15) * 8;
        float4 a0 = *(const float4*)(w1 + k * 128 + n0);
        float4 a1 = *(const float4*)(w1 + k * 128 + n0 + 4);
        w1S[swe64(n0 + 0, k)] = f2bf(a0.x);
        w1S[swe64(n0 + 1, k)] = f2bf(a0.y);
        w1S[swe64(n0 + 2, k)] = f2bf(a0.z);
        w1S[swe64(n0 + 3, k)] = f2bf(a0.w);
        w1S[swe64(n0 + 4, k)] = f2bf(a1.x);
        w1S[swe64(n0 + 5, k)] = f2bf(a1.y);
        w1S[swe64(n0 + 6, k)] = f2bf(a1.z);
        w1S[swe64(n0 + 7, k)] = f2bf(a1.w);
    }
    {
        int k = t >> 1;
        int half = t & 1;
        int n0 = half ? 38 : 0, n1 = half ? 75 : 38;
        for (int n = n0; n < n1; ++n)
            w2S[swe(n, k)] = f2bf(w2[k * 75 + n]);
    }
    if (t < 128) b1S[t] = b1[t];
    if (t < 80)  b2S[t] = (t < 75) ? b2[t] : 0.f;
    __syncthreads();

    int w = t >> 6, lane = t & 63, lr = lane & 15, lg = lane >> 4;

    f32x4 acc[2][8];
    #pragma unroll
    for (int mi = 0; mi < 2; ++mi)
        #pragma unroll
        for (int ni = 0; ni < 8; ++ni)
            acc[mi][ni] = (f32x4){0.f, 0.f, 0.f, 0.f};

    short8v af[2];
    #pragma unroll
    for (int mi = 0; mi < 2; ++mi) {
        int m = w * 32 + mi * 16 + lr;
        int R = blockIdx.x * 128 + m;
        int b = R / 169, tt = R - 169 * b;
        if (lg < 2) {
            const float* zp = latent + (size_t)b * 7056 + tt * 16 + lg * 8;
            float4 f0 = *(const float4*)(zp);
            float4 f1 = *(const float4*)(zp + 4);
            af[mi][0] = (short)f2bf(f0.x); af[mi][1] = (short)f2bf(f0.y);
            af[mi][2] = (short)f2bf(f0.z); af[mi][3] = (short)f2bf(f0.w);
            af[mi][4] = (short)f2bf(f1.x); af[mi][5] = (short)f2bf(f1.y);
            af[mi][6] = (short)f2bf(f1.z); af[mi][7] = (short)f2bf(f1.w);
        } else {
            af[mi] = (short8v){0,0,0,0,0,0,0,0};
        }
    }
    {
        int kb = lg * 8;
        #pragma unroll
        for (int ni = 0; ni < 8; ++ni) {
            short8v bf = *(const short8v*)&w1S[swe64(ni * 16 + lr, kb)];
            acc[0][ni] = __builtin_amdgcn_mfma_f32_16x16x32_bf16(af[0], bf, acc[0][ni], 0, 0, 0);
            acc[1][ni] = __builtin_amdgcn_mfma_f32_16x16x32_bf16(af[1], bf, acc[1][ni], 0, 0, 0);
        }
    }
    #pragma unroll
    for (int mi = 0; mi < 2; ++mi)
        #pragma unroll
        for (int ni = 0; ni < 8; ++ni) {
            int n = ni * 16 + lr;
            float bv = b1S[n];
            #pragma unroll
            for (int r = 0; r < 4; ++r) {
                int m = w * 32 + mi * 16 + lg * 4 + r;
                hS[swe(m, n)] = f2bf(fmaxf(acc[mi][ni][r] + bv, 0.f));
            }
        }

    f32x4 acc2[2][5];
    #pragma unroll
    for (int mi = 0; mi < 2; ++mi)
        #pragma unroll
        for (int ni = 0; ni < 5; ++ni)
            acc2[mi][ni] = (f32x4){0.f, 0.f, 0.f, 0.f};

    #pragma unroll
    for (int kh = 0; kh < 4; ++kh) {
        int kb = kh * 32 + lg * 8;
        short8v a0 = *(const short8v*)&hS[swe(w * 32 + lr, kb)];
        short8v a1 = *(const short8v*)&hS[swe(w * 32 + 16 + lr, kb)];
        #pragma unroll
        for (int ni = 0; ni < 5; ++ni) {
            short8v bf = *(const short8v*)&w2S[swe(ni * 16 + lr, kb)];
            acc2[0][ni] = __builtin_amdgcn_mfma_f32_16x16x32_bf16(a0, bf, acc2[0][ni], 0, 0, 0);
            acc2[1][ni] = __builtin_amdgcn_mfma_f32_16x16x32_bf16(a1, bf, acc2[1][ni], 0, 0, 0);
        }
    }

    #pragma unroll
    for (int mi = 0; mi < 2; ++mi)
        #pragma unroll
        for (int r = 0; r < 4; ++r) {
            int m = w * 32 + mi * 16 + lg * 4 + r;
            int R = blockIdx.x * 128 + m;
            int b = R / 169, tt = R - 169 * b;
            int ti = tt / 13, tj = tt - 13 * ti;
            #pragma unroll
            for (int ni = 0; ni < 5; ++ni) {
                int col = ni * 16 + lr;
                if (col < 75) {
                    float a = acc2[mi][ni][r] + b2S[col];
                    float o = 1.f / (1.f + expf(-a));
                    int c = col / 25, o25 = col - 25 * c;
                    int ph = o25 / 5, pw = o25 - 5 * ph;
                    int y = ti * 5 + ph, xx = tj * 5 + pw;
                    if (y < 64 && xx < 64)
                        img[(((size_t)b * 3 + c) * 64 + y) * 64 + xx] = o;
                }
            }
        }
}

// ======= split-K bf16 MFMA GEMM v8: depth-2 counted-vmcnt pipeline ==========
// BM=128 x BN=128 x BK=64. 256 thr = 4 waves (2Mx2N), wave tile 64x64.
// LDS dbuf 64 KB -> 2 blocks/CU. Two static register sets; loads issued TWO
// steps early (fly across 2 raw barriers; lgkmcnt(0)-only fences).
// Grid (N/128, 2 m-halves, S k-chunks).
// EPI=1: plain stores to partials C[z][256][N]. EPI=0: atomic into zeroed C.
template<int EPI>
__global__ __launch_bounds__(256, 2) void k_gemm_pipe(
    const unsigned short* __restrict__ A,
    const float* __restrict__ W,
    float* __restrict__ C,
    int N, int K, int baseSteps)
{
    __shared__ __align__(16) unsigned short As[2][128 * 64];  // 2 x 16 KB
    __shared__ __align__(16) unsigned short Ws[2][128 * 64];  // 2 x 16 KB

    int t = threadIdx.x;
    int bn = blockIdx.x * 128;
    int m0 = blockIdx.y * 128;
    int totalSteps = (K + 63) >> 6;
    int step0 = blockIdx.z * baseSteps;
    int nSteps = totalSteps - step0;
    if (nSteps > baseSteps) nSteps = baseSteps;
    if (nSteps <= 0) return;
    const bool nfull = (bn + 128 <= N);

    int w = t >> 6, lane = t & 63, lr = lane & 15, lg = lane >> 4;
    int wr = w >> 1, wc = w & 1;

    // A staging: 128 rows x 64 ushorts; thread: row ar=t>>1, half ah=(t&1)*32
    int ar = t >> 1, ah = (t & 1) * 32;
    const unsigned short* Arow = A + (size_t)(m0 + ar) * K + ah;

    // W staging: 64 k-rows x 128 cols fp32; thread: col-quad nq=t&31 (4 cols),
    // k-rows kb..kb+7 with kb=(t>>5)*8  -> per-k-row 512B contiguous reads
    int nq = t & 31, kb = (t >> 5) * 8;
    int nc = bn + 4 * nq;

    uint4  aPa[4], aPb[4];
    float4 wPa[8], wPb[8];

    f32x4 acc[4][4];
    #pragma unroll
    for (int i = 0; i < 4; ++i)
        #pragma unroll
        for (int j = 0; j < 4; ++j)
            acc[i][j] = (f32x4){0.f, 0.f, 0.f, 0.f};

    #define LOAD_T(AP, WP, stepIdx)                                           \
    do {                                                                      \
        int kk0 = (stepIdx) << 6;                                             \
        if ((kk0 + 64 <= K) && nfull) {                                       \
            const uint4* ap = (const uint4*)(Arow + kk0);                     \
            _Pragma("unroll")                                                 \
            for (int u = 0; u < 4; ++u) AP[u] = ap[u];                        \
            const float* wp = W + (size_t)(kk0 + kb) * N + nc;                \
            _Pragma("unroll")                                                 \
            for (int jj = 0; jj < 8; ++jj)                                    \
                WP[jj] = *(const float4*)(wp + (size_t)jj * N);               \
        } else {                                                              \
            _Pragma("unroll")                                                 \
            for (int u = 0; u < 4; ++u) {                                     \
                int ak = kk0 + ah + u * 8;                                    \
                if (ak + 8 <= K) AP[u] = *(const uint4*)(Arow + kk0 + u * 8); \
                else             AP[u] = make_uint4(0, 0, 0, 0);              \
            }                                                                 \
            _Pragma("unroll")                                                 \
            for (int jj = 0; jj < 8; ++jj) {                                  \
                int kr = kk0 + kb + jj;                                       \
                float4 tmp = {0.f, 0.f, 0.f, 0.f};                            \
                if (kr < K) {                                                 \
                    const float* wp = W + (size_t)kr * N;                     \
                    if (nfull) tmp = *(const float4*)(wp + nc);               \
                    else {                                                    \
                        tmp.x = (nc + 0 < N) ? wp[nc + 0] : 0.f;              \
                        tmp.y = (nc + 1 < N) ? wp[nc + 1] : 0.f;              \
                        tmp.z = (nc + 2 < N) ? wp[nc + 2] : 0.f;              \
                        tmp.w = (nc + 3 < N) ? wp[nc + 3] : 0.f;              \
                    }                                                         \
                }                                                             \
                WP[jj] = tmp;                                                 \
            }                                                                 \
        }                                                                     \
    } while (0)

    #define STORE_T(buf, AP, WP)                                              \
    do {                                                                      \
        _Pragma("unroll")                                                     \
        for (int u = 0; u < 4; ++u)                                           \
            *(uint4*)&As[buf][swe64(ar, ah + u * 8)] = AP[u];                 \
        _Pragma("unroll")                                                     \
        for (int c4 = 0; c4 < 4; ++c4) {                                      \
            int n = 4 * nq + c4;                                              \
            u16x8 pk;                                                         \
            _Pragma("unroll")                                                 \
            for (int jj = 0; jj < 8; ++jj) {                                  \
                float e = (c4 == 0) ? WP[jj].x : (c4 == 1) ? WP[jj].y         \
                        : (c4 == 2) ? WP[jj].z : WP[jj].w;                    \
                pk[jj] = f2bf(e);                                             \
            }                                                                 \
            *(u16x8*)&Ws[buf][swn(n, kb)] = pk;                               \
        }                                                                     \
    } while (0)

    #define MFMA_T(buf)                                                       \
    do {                                                                      \
        _Pragma("unroll")                                                     \
        for (int kk = 0; kk < 64; kk += 32) {                                 \
            int kbase = kk + lg * 8;                                          \
            short8v afr[4], bfr[4];                                           \
            _Pragma("unroll")                                                 \
            for (int mi = 0; mi < 4; ++mi)                                    \
                afr[mi] = *(const short8v*)&As[buf][                          \
                    swe64(wr * 64 + mi * 16 + lr, kbase)];                    \
            _Pragma("unroll")                                                 \
            for (int ni = 0; ni < 4; ++ni)                                    \
                bfr[ni] = *(const short8v*)&Ws[buf][                          \
                    swn(wc * 64 + ni * 16 + lr, kbase)];                      \
            _Pragma("unroll")                                                 \
            for (int mi = 0; mi < 4; ++mi)                                    \
                _Pragma("unroll")                                             \
                for (int ni = 0; ni < 4; ++ni)                                \
                    acc[mi][ni] = __builtin_amdgcn_mfma_f32_16x16x32_bf16(    \
                        afr[mi], bfr[ni], acc[mi][ni], 0, 0, 0);              \
        }                                                                     \
    } while (0)

    #define FENCE_BAR                                                         \
    do {                                                                      \
        asm volatile("s_waitcnt lgkmcnt(0)" ::: "memory");                    \
        __builtin_amdgcn_s_barrier();                                         \
        __builtin_amdgcn_sched_barrier(0);                                    \
    } while (0)

    // prologue: tile0 -> buf0 (barriered); sB holds tile1; sA refilled tile2
    LOAD_T(aPa, wPa, step0);
    if (nSteps > 1) LOAD_T(aPb, wPb, step0 + 1);
    STORE_T(0, aPa, wPa);
    if (nSteps > 2) LOAD_T(aPa, wPa, step0 + 2);
    FENCE_BAR;

    for (int ti = 0; ti < nSteps; ti += 2) {
        // even step: compute buf0; stage tile ti+1 (in sB) into buf1
        if (ti + 1 < nSteps) {
            STORE_T(1, aPb, wPb);                 // vmcnt waits only sB loads
            if (ti + 3 < nSteps) LOAD_T(aPb, wPb, step0 + ti + 3);
        }
        __builtin_amdgcn_s_setprio(1);
        MFMA_T(0);
        __builtin_amdgcn_s_setprio(0);
        FENCE_BAR;
        if (ti + 1 >= nSteps) break;
        // odd step: compute buf1; stage tile ti+2 (in sA) into buf0
        if (ti + 2 < nSteps) {
            STORE_T(0, aPa, wPa);
            if (ti + 4 < nSteps) LOAD_T(aPa, wPa, step0 + ti + 4);
        }
        __builtin_amdgcn_s_setprio(1);
        MFMA_T(1);
        __builtin_amdgcn_s_setprio(0);
        FENCE_BAR;
    }
    #undef LOAD_T
    #undef STORE_T
    #undef MFMA_T
    #undef FENCE_BAR

    if (EPI == 1) {
        float* Cz = C + (size_t)blockIdx.z * 256 * N;
        #pragma unroll
        for (int ni = 0; ni < 4; ++ni) {
            int col = bn + wc * 64 + ni * 16 + lr;
            if (col < N) {
                #pragma unroll
                for (int mi = 0; mi < 4; ++mi) {
                    int row = m0 + wr * 64 + mi * 16 + lg * 4;
                    #pragma unroll
                    for (int r = 0; r < 4; ++r)
                        Cz[(size_t)(row + r) * N + col] = acc[mi][ni][r];
                }
            }
        }
    } else {
        #pragma unroll
        for (int ni = 0; ni < 4; ++ni) {
            int col = bn + wc * 64 + ni * 16 + lr;
            if (col < N) {
                #pragma unroll
                for (int mi = 0; mi < 4; ++mi) {
                    int row = m0 + wr * 64 + mi * 16 + lg * 4;
                    #pragma unroll
                    for (int r = 0; r < 4; ++r)
                        __hip_atomic_fetch_add(&C[(size_t)(row + r) * N + col],
                                               acc[mi][ni][r],
                                               __ATOMIC_RELAXED,
                                               __HIP_MEMORY_SCOPE_AGENT);
                }
            }
        }
    }
}

// ---------- reduce partials + bias + relu (GEMM2 epilogue) ----------------
__global__ __launch_bounds__(256) void k_reduce_bias_relu(
    const float* __restrict__ parts, const float* __restrict__ bias,
    float* __restrict__ out, int S, int N)
{
    int nF4 = (256 / 4) * N;
    int nCol4 = N >> 2;
    size_t strideF4 = (size_t)64 * N;
    for (int idx = blockIdx.x * 256 + threadIdx.x; idx < nF4;
         idx += gridDim.x * 256) {
        int col4 = idx % nCol4;
        float4 b = *(const float4*)(bias + col4 * 4);
        float4 a = ((const float4*)parts)[idx];
        for (int z = 1; z < S; ++z) {
            float4 p = ((const float4*)parts)[(size_t)z * strideF4 + idx];
            a.x += p.x; a.y += p.y; a.z += p.z; a.w += p.w;
        }
        a.x = fmaxf(a.x + b.x, 0.f);
        a.y = fmaxf(a.y + b.y, 0.f);
        a.z = fmaxf(a.z + b.z, 0.f);
        a.w = fmaxf(a.w + b.w, 0.f);
        ((float4*)out)[idx] = a;
    }
}

// ---------- stats partial, FUSED with GEMM1 reduce+bias+relu ---------------
// hs[mm][kk] = relu(sum_z parts[z] + enc_b1); then psum = hs @ w2 chunk.
__global__ __launch_bounds__(256) void k_stats_partial(
    const float* __restrict__ parts,   // S x (256 x 4096) raw partials
    const float* __restrict__ enc_b1,
    const float* __restrict__ w2,
    float* __restrict__ psum,
    int S)
{
    __shared__ float hs[16][256];
    int mg = blockIdx.x >> 4;
    int ks = blockIdx.x & 15;
    int t = threadIdx.x;

    for (int i = t; i < 16 * 256; i += 256) {
        int mm = i >> 8, kk = i & 255;
        size_t off = (size_t)(mg * 16 + mm) * 4096 + ks * 256 + kk;
        float v = enc_b1[ks * 256 + kk];
        for (int z = 0; z < S; ++z)
            v += parts[(size_t)z * 1048576 + off];
        hs[mm][kk] = fmaxf(v, 0.f);
    }
    __syncthreads();

    int n = t & 127, mh = t >> 7;
    float acc[8] = {0.f,0.f,0.f,0.f,0.f,0.f,0.f,0.f};
    const float* w2p = w2 + (size_t)(ks * 256) * 128 + n;
    for (int k = 0; k < 256; ++k) {
        float wv = w2p[(size_t)k * 128];
        #pragma unroll
        for (int mm = 0; mm < 8; ++mm)
            acc[mm] += hs[mh * 8 + mm][k] * wv;
    }
    #pragma unroll
    for (int mm = 0; mm < 8; ++mm) {
        int m = mg * 16 + mh * 8 + mm;
        psum[((size_t)m * 16 + ks) * 128 + n] = acc[mm];
    }
}

// ---------- mid2 (unchanged) ----------
__global__ __launch_bounds__(256) void k_mid2(
    const float* __restrict__ psum,
    const float* __restrict__ enc_b2,
    const float* __restrict__ noise_z,
    const float* __restrict__ dec_w1, const float* __restrict__ dec_b1,
    const float* __restrict__ dec_w2, const float* __restrict__ dec_b2,
    float* __restrict__ mean_out, float* __restrict__ logvar_out,
    unsigned short* __restrict__ h2bf)
{
    __shared__ float st[128];
    __shared__ float z_s[64];
    __shared__ float h1_s[32];

    int m = blockIdx.x >> 2, ch = blockIdx.x & 3;
    int t = threadIdx.x;

    if (t < 128) {
        float a = enc_b2[t];
        #pragma unroll 4
        for (int ks = 0; ks < 16; ++ks)
            a += psum[((size_t)m * 16 + ks) * 128 + t];
        st[t] = fmaxf(a, 0.f);
    }
    __syncthreads();

    if (t < 64) {
        float mean = st[t], lv = st[t + 64];
        if (ch == 0) {
            mean_out[(size_t)m * 64 + t]   = mean;
            logvar_out[(size_t)m * 64 + t] = lv;
        }
        z_s[t] = noise_z[(size_t)m * 64 + t] * expf(0.5f * lv) + mean;
    }
    __syncthreads();

    if (t < 32) {
        float a = dec_b1[t];
        #pragma unroll 8
        for (int k = 0; k < 64; ++k) a += z_s[k] * dec_w1[k * 32 + t];
        h1_s[t] = fmaxf(a, 0.f);
    }
    __syncthreads();

    #pragma unroll
    for (int j = 0; j < 4; ++j) {
        int nn = ch * 1024 + j * 256 + t;
        float a = dec_b2[nn];
        #pragma unroll 8
        for (int k = 0; k < 32; ++k)
            a += h1_s[k] * dec_w2[(size_t)k * 4096 + nn];
        h2bf[(size_t)m * 4096 + nn] = f2bf(fmaxf(a, 0.f));
    }
}

extern "C" void kernel_launch(void* const* d_in, const int* in_sizes, int n_in,
                              void* d_out, int out_size, void* d_ws, size_t ws_size,
                              hipStream_t stream) {
    const float* x            = (const float*)d_in[0];
    const float* noise_little = (const float*)d_in[1];
    const float* noise_z      = (const float*)d_in[2];
    const float* le_w1        = (const float*)d_in[3];
    const float* le_b1        = (const float*)d_in[4];
    const float* le_w2        = (const float*)d_in[5];
    const float* le_b2        = (const float*)d_in[6];
    const float* ld_w1        = (const float*)d_in[7];
    const float* ld_b1        = (const float*)d_in[8];
    const float* ld_w2        = (const float*)d_in[9];
    const float* ld_b2        = (const float*)d_in[10];
    const float* enc_w1       = (const float*)d_in[11];
    const float* enc_b1       = (const float*)d_in[12];
    const float* enc_w2       = (const float*)d_in[13];
    const float* enc_b2       = (const float*)d_in[14];
    const float* dec_w1       = (const float*)d_in[15];
    const float* dec_b1       = (const float*)d_in[16];
    const float* dec_w2       = (const float*)d_in[17];
    const float* dec_b2       = (const float*)d_in[18];
    const float* dec_w3       = (const float*)d_in[19];
    const float* dec_b3       = (const float*)d_in[20];

    float* out = (float*)d_out;
    float* latent = out;                       // 1,806,336
    float* mean   = latent + 1806336;          // 16,384
    float* logvar = mean + 16384;              // 16,384
    float* nli    = logvar + 16384;            // 1,806,336
    float* img    = nli + 1806336;             // 3,145,728

    float* h_e = latent;   // fallback-only raw accumulator

    unsigned short* nli_bf = (unsigned short*)d_ws;                   // 3,612,672 B
    float* psum = (float*)((char*)d_ws + 3612672);                    // 2,097,152 B
    unsigned short* h2bf = (unsigned short*)((char*)d_ws + 5709824);  // 2,097,152 B
    float* parts = (float*)((char*)d_ws + 7806976);

    const size_t base = 7806976;
    const size_t slice1 = (size_t)256 * 4096 * 4;   // 4 MB
    const size_t slice2 = (size_t)256 * 7056 * 4;   // 7.2 MB
    const int S1 = (ws_size >= base + 8 * slice1) ? 8 : 0;
    const int S2 = (ws_size >= base + 4 * slice2) ? 4 : 0;

    // 1) patches + little_encode + reparam (MFMA)
    k_little_encode_mfma<<<882, 256, 0, stream>>>(
        x, noise_little, le_w1, le_b1, le_w2, le_b2, nli, nli_bf);

    // 2) GEMM1 partials [256x7056 @ 7056x4096]; K-steps = 111
    if (S1) {
        k_gemm_pipe<1><<<dim3(32, 2, 8), 256, 0, stream>>>(
            nli_bf, enc_w1, parts, 4096, 7056, 14);
        // 3a) stats (fused reduce+bias+relu)
        k_stats_partial<<<256, 256, 0, stream>>>(parts, enc_b1, enc_w2, psum, 8);
    } else {
        hipMemsetAsync(h_e, 0, slice1, stream);
        k_gemm_pipe<0><<<dim3(32, 2, 8), 256, 0, stream>>>(
            nli_bf, enc_w1, h_e, 4096, 7056, 14);
        k_stats_partial<<<256, 256, 0, stream>>>(h_e, enc_b1, enc_w2, psum, 1);
    }

    // 3b) reduce + reparam + dec1 + dec2
    k_mid2<<<1024, 256, 0, stream>>>(
        psum, enc_b2, noise_z, dec_w1, dec_b1, dec_w2, dec_b2,
        mean, logvar, h2bf);

    // 4) GEMM2 [256x4096 @ 4096x7056]; K-steps = 64
    if (S2) {
        k_gemm_pipe<1><<<dim3(56, 2, 4), 256, 0, stream>>>(
            h2bf, dec_w3, parts, 7056, 4096, 16);
        k_reduce_bias_relu<<<1764, 256, 0, stream>>>(
            parts, dec_b3, latent, 4, 7056);
    } else {
        hipMemsetAsync(latent, 0, slice2, stream);
        k_gemm_pipe<0><<<dim3(56, 2, 4), 256, 0, stream>>>(
            h2bf, dec_w3, latent, 7056, 4096, 16);
        k_reduce_bias_relu<<<1764, 256, 0, stream>>>(
            latent, dec_b3, latent, 1, 7056);
    }

    // 5) little_decode + canvas (MFMA)
    k_little_decode_mfma<<<338, 256, 0, stream>>>(
        latent, ld_w1, ld_b1, ld_w2, ld_b2, img);
}

// Round 13
// 225.037 us; speedup vs baseline: 1.0324x; 1.0324x over previous
//
#include <hip/hip_runtime.h>
#include <math.h>

#define EPSF 1e-6f

typedef __attribute__((ext_vector_type(8))) short short8v;
typedef __attribute__((ext_vector_type(4))) float f32x4;
typedef __attribute__((ext_vector_type(4))) unsigned short u16x4;

__device__ __forceinline__ unsigned short f2bf(float f) {
    union { float f; unsigned u; } v; v.f = f;
    return (unsigned short)((v.u + 0x7FFFu + ((v.u >> 16) & 1u)) >> 16);
}
// XOR swizzle for [row][128-ushort] LDS tiles (16B granularity)
__device__ __forceinline__ int swe(int row, int k) {
    return (row << 7) + (k ^ ((row & 7) << 3));
}
// XOR swizzle for [row][64-ushort] LDS tiles
__device__ __forceinline__ int swe64(int row, int k) {
    return (row << 6) + (k ^ ((row & 7) << 3));
}

// ================= little_encode via MFMA (unchanged, verified) =============
__global__ __launch_bounds__(256) void k_little_encode_mfma(
    const float* __restrict__ x,
    const float* __restrict__ noise,
    const float* __restrict__ w1,
    const float* __restrict__ b1,
    const float* __restrict__ w2,
    const float* __restrict__ b2,
    float* __restrict__ nli,
    unsigned short* __restrict__ nli_bf)
{
    __shared__ __align__(16) unsigned short pS[128 * 128];
    __shared__ __align__(16) unsigned short w1S[128 * 128];
    __shared__ __align__(16) unsigned short hS[128 * 128];
    __shared__ __align__(16) unsigned short w2S[32 * 128];
    __shared__ float b1S[128];
    __shared__ float b2S[32];
    __shared__ float sums[128][4];

    int t = threadIdx.x;

    {
        uint4 z4 = make_uint4(0, 0, 0, 0);
        #pragma unroll
        for (int i = 0; i < 8; ++i) {
            *(uint4*)&pS[(i * 256 + t) * 8]  = z4;
            *(uint4*)&w1S[(i * 256 + t) * 8] = z4;
        }
    }
    __syncthreads();

    for (int k = (t >> 4); k < 75; k += 16) {
        int n0 = (t & 15) * 8;
        float4 a0 = *(const float4*)(w1 + k * 128 + n0);
        float4 a1 = *(const float4*)(w1 + k * 128 + n0 + 4);
        w1S[swe(n0 + 0, k)] = f2bf(a0.x);
        w1S[swe(n0 + 1, k)] = f2bf(a0.y);
        w1S[swe(n0 + 2, k)] = f2bf(a0.z);
        w1S[swe(n0 + 3, k)] = f2bf(a0.w);
        w1S[swe(n0 + 4, k)] = f2bf(a1.x);
        w1S[swe(n0 + 5, k)] = f2bf(a1.y);
        w1S[swe(n0 + 6, k)] = f2bf(a1.z);
        w1S[swe(n0 + 7, k)] = f2bf(a1.w);
    }
    for (int k = (t >> 3); k < 128; k += 32) {
        int n0 = (t & 7) * 4;
        float4 a = *(const float4*)(w2 + k * 32 + n0);
        w2S[swe(n0 + 0, k)] = f2bf(a.x);
        w2S[swe(n0 + 1, k)] = f2bf(a.y);
        w2S[swe(n0 + 2, k)] = f2bf(a.z);
        w2S[swe(n0 + 3, k)] = f2bf(a.w);
    }
    if (t < 128) b1S[t] = b1[t];
    if (t < 32)  b2S[t] = b2[t];

    int row  = t & 127;
    int half = t >> 7;
    int R0 = blockIdx.x * 128 + row;
    int bb = R0 / 441;
    int p  = R0 - bb * 441;
    int pi = p / 21, pj = p - pi * 21;
    const float* xb = x + (size_t)bb * 3 * 63 * 63;

    float v[38];
    {
        float sA = 0.f, sB = 0.f;
        if (half == 0) {
            #pragma unroll
            for (int i = 0; i < 38; ++i) {
                const int k = i;
                const int c = k / 25, o = k % 25, ph = o / 5, pw = o % 5;
                int y = pi * 3 + ph - 1, xx = pj * 3 + pw - 1;
                float val = 0.f;
                if ((unsigned)y < 63u && (unsigned)xx < 63u)
                    val = xb[(c * 63 + y) * 63 + xx];
                v[i] = val;
                if (k < 25) sA += val; else sB += val;
            }
        } else {
            #pragma unroll
            for (int i = 0; i < 37; ++i) {
                const int k = 38 + i;
                const int c = k / 25, o = k % 25, ph = o / 5, pw = o % 5;
                int y = pi * 3 + ph - 1, xx = pj * 3 + pw - 1;
                float val = 0.f;
                if ((unsigned)y < 63u && (unsigned)xx < 63u)
                    val = xb[(c * 63 + y) * 63 + xx];
                v[i] = val;
                if (k < 50) sA += val; else sB += val;
            }
        }
        sums[row][half * 2 + 0] = sA;
        sums[row][half * 2 + 1] = sB;
    }
    __syncthreads();
    {
        float c0 = sums[row][0];
        float c1 = sums[row][1] + sums[row][2];
        float c2 = sums[row][3];
        if (half == 0) {
            #pragma unroll
            for (int i = 0; i < 38; ++i) {
                const int k = i;
                float cs = (k < 25) ? c0 : c1;
                pS[swe(row, k)] = f2bf(v[i] + EPSF * cs);
            }
        } else {
            #pragma unroll
            for (int i = 0; i < 37; ++i) {
                const int k = 38 + i;
                float cs = (k < 50) ? c1 : c2;
                pS[swe(row, k)] = f2bf(v[i] + EPSF * cs);
            }
        }
    }
    __syncthreads();

    int w = t >> 6, lane = t & 63, lr = lane & 15, lg = lane >> 4;

    f32x4 acc[2][8];
    #pragma unroll
    for (int mi = 0; mi < 2; ++mi)
        #pragma unroll
        for (int ni = 0; ni < 8; ++ni)
            acc[mi][ni] = (f32x4){0.f, 0.f, 0.f, 0.f};

    #pragma unroll
    for (int ks = 0; ks < 3; ++ks) {
        int kb = ks * 32 + lg * 8;
        short8v a0 = *(const short8v*)&pS[swe(w * 32 + lr, kb)];
        short8v a1 = *(const short8v*)&pS[swe(w * 32 + 16 + lr, kb)];
        #pragma unroll
        for (int ni = 0; ni < 8; ++ni) {
            short8v bf = *(const short8v*)&w1S[swe(ni * 16 + lr, kb)];
            acc[0][ni] = __builtin_amdgcn_mfma_f32_16x16x32_bf16(a0, bf, acc[0][ni], 0, 0, 0);
            acc[1][ni] = __builtin_amdgcn_mfma_f32_16x16x32_bf16(a1, bf, acc[1][ni], 0, 0, 0);
        }
    }
    #pragma unroll
    for (int mi = 0; mi < 2; ++mi)
        #pragma unroll
        for (int ni = 0; ni < 8; ++ni) {
            int n = ni * 16 + lr;
            float bv = b1S[n];
            #pragma unroll
            for (int r = 0; r < 4; ++r) {
                int m = w * 32 + mi * 16 + lg * 4 + r;
                hS[swe(m, n)] = f2bf(fmaxf(acc[mi][ni][r] + bv, 0.f));
            }
        }

    f32x4 acc2[2][2];
    #pragma unroll
    for (int mi = 0; mi < 2; ++mi)
        #pragma unroll
        for (int ni = 0; ni < 2; ++ni)
            acc2[mi][ni] = (f32x4){0.f, 0.f, 0.f, 0.f};

    #pragma unroll
    for (int kh = 0; kh < 4; ++kh) {
        int kb = kh * 32 + lg * 8;
        short8v a0 = *(const short8v*)&hS[swe(w * 32 + lr, kb)];
        short8v a1 = *(const short8v*)&hS[swe(w * 32 + 16 + lr, kb)];
        #pragma unroll
        for (int ni = 0; ni < 2; ++ni) {
            short8v bf = *(const short8v*)&w2S[swe(ni * 16 + lr, kb)];
            acc2[0][ni] = __builtin_amdgcn_mfma_f32_16x16x32_bf16(a0, bf, acc2[0][ni], 0, 0, 0);
            acc2[1][ni] = __builtin_amdgcn_mfma_f32_16x16x32_bf16(a1, bf, acc2[1][ni], 0, 0, 0);
        }
    }

    #pragma unroll
    for (int mi = 0; mi < 2; ++mi)
        #pragma unroll
        for (int r = 0; r < 4; ++r) {
            int m = w * 32 + mi * 16 + lg * 4 + r;
            size_t R = (size_t)blockIdx.x * 128 + m;
            float mean = acc2[mi][0][r] + b2S[lr];
            float lv   = acc2[mi][1][r] + b2S[16 + lr];
            float z = noise[R * 16 + lr] * expf(0.5f * lv) + mean;
            nli[R * 16 + lr] = z;
            nli_bf[R * 16 + lr] = f2bf(z);
        }
}

// ================= little_decode via MFMA (unchanged, verified) =============
__global__ __launch_bounds__(256) void k_little_decode_mfma(
    const float* __restrict__ latent,
    const float* __restrict__ w1,
    const float* __restrict__ b1,
    const float* __restrict__ w2,
    const float* __restrict__ b2,
    float* __restrict__ img)
{
    __shared__ __align__(16) unsigned short w1S[128 * 64];
    __shared__ __align__(16) unsigned short hS[128 * 128];
    __shared__ __align__(16) unsigned short w2S[80 * 128];
    __shared__ float b1S[128];
    __shared__ float b2S[80];

    int t = threadIdx.x;

    {
        uint4 z4 = make_uint4(0, 0, 0, 0);
        #pragma unroll
        for (int i = 0; i < 4; ++i)
            *(uint4*)&w1S[(i * 256 + t) * 8] = z4;
        #pragma unroll
        for (int i = 0; i < 5; ++i)
            *(uint4*)&w2S[(i * 256 + t) * 8] = z4;
    }
    __syncthreads();

    {
        int k = t >> 4;
        int n0 = (t & 15) * 8;
        float4 a0 = *(const float4*)(w1 + k * 128 + n0);
        float4 a1 = *(const float4*)(w1 + k * 128 + n0 + 4);
        w1S[swe64(n0 + 0, k)] = f2bf(a0.x);
        w1S[swe64(n0 + 1, k)] = f2bf(a0.y);
        w1S[swe64(n0 + 2, k)] = f2bf(a0.z);
        w1S[swe64(n0 + 3, k)] = f2bf(a0.w);
        w1S[swe64(n0 + 4, k)] = f2bf(a1.x);
        w1S[swe64(n0 + 5, k)] = f2bf(a1.y);
        w1S[swe64(n0 + 6, k)] = f2bf(a1.z);
        w1S[swe64(n0 + 7, k)] = f2bf(a1.w);
    }
    {
        int k = t >> 1;
        int half = t & 1;
        int n0 = half ? 38 : 0, n1 = half ? 75 : 38;
        for (int n = n0; n < n1; ++n)
            w2S[swe(n, k)] = f2bf(w2[k * 75 + n]);
    }
    if (t < 128) b1S[t] = b1[t];
    if (t < 80)  b2S[t] = (t < 75) ? b2[t] : 0.f;
    __syncthreads();

    int w = t >> 6, lane = t & 63, lr = lane & 15, lg = lane >> 4;

    f32x4 acc[2][8];
    #pragma unroll
    for (int mi = 0; mi < 2; ++mi)
        #pragma unroll
        for (int ni = 0; ni < 8; ++ni)
            acc[mi][ni] = (f32x4){0.f, 0.f, 0.f, 0.f};

    short8v af[2];
    #pragma unroll
    for (int mi = 0; mi < 2; ++mi) {
        int m = w * 32 + mi * 16 + lr;
        int R = blockIdx.x * 128 + m;
        int b = R / 169, tt = R - 169 * b;
        if (lg < 2) {
            const float* zp = latent + (size_t)b * 7056 + tt * 16 + lg * 8;
            float4 f0 = *(const float4*)(zp);
            float4 f1 = *(const float4*)(zp + 4);
            af[mi][0] = (short)f2bf(f0.x); af[mi][1] = (short)f2bf(f0.y);
            af[mi][2] = (short)f2bf(f0.z); af[mi][3] = (short)f2bf(f0.w);
            af[mi][4] = (short)f2bf(f1.x); af[mi][5] = (short)f2bf(f1.y);
            af[mi][6] = (short)f2bf(f1.z); af[mi][7] = (short)f2bf(f1.w);
        } else {
            af[mi] = (short8v){0,0,0,0,0,0,0,0};
        }
    }
    {
        int kb = lg * 8;
        #pragma unroll
        for (int ni = 0; ni < 8; ++ni) {
            short8v bf = *(const short8v*)&w1S[swe64(ni * 16 + lr, kb)];
            acc[0][ni] = __builtin_amdgcn_mfma_f32_16x16x32_bf16(af[0], bf, acc[0][ni], 0, 0, 0);
            acc[1][ni] = __builtin_amdgcn_mfma_f32_16x16x32_bf16(af[1], bf, acc[1][ni], 0, 0, 0);
        }
    }
    #pragma unroll
    for (int mi = 0; mi < 2; ++mi)
        #pragma unroll
        for (int ni = 0; ni < 8; ++ni) {
            int n = ni * 16 + lr;
            float bv = b1S[n];
            #pragma unroll
            for (int r = 0; r < 4; ++r) {
                int m = w * 32 + mi * 16 + lg * 4 + r;
                hS[swe(m, n)] = f2bf(fmaxf(acc[mi][ni][r] + bv, 0.f));
            }
        }

    f32x4 acc2[2][5];
    #pragma unroll
    for (int mi = 0; mi < 2; ++mi)
        #pragma unroll
        for (int ni = 0; ni < 5; ++ni)
            acc2[mi][ni] = (f32x4){0.f, 0.f, 0.f, 0.f};

    #pragma unroll
    for (int kh = 0; kh < 4; ++kh) {
        int kb = kh * 32 + lg * 8;
        short8v a0 = *(const short8v*)&hS[swe(w * 32 + lr, kb)];
        short8v a1 = *(const short8v*)&hS[swe(w * 32 + 16 + lr, kb)];
        #pragma unroll
        for (int ni = 0; ni < 5; ++ni) {
            short8v bf = *(const short8v*)&w2S[swe(ni * 16 + lr, kb)];
            acc2[0][ni] = __builtin_amdgcn_mfma_f32_16x16x32_bf16(a0, bf, acc2[0][ni], 0, 0, 0);
            acc2[1][ni] = __builtin_amdgcn_mfma_f32_16x16x32_bf16(a1, bf, acc2[1][ni], 0, 0, 0);
        }
    }

    #pragma unroll
    for (int mi = 0; mi < 2; ++mi)
        #pragma unroll
        for (int r = 0; r < 4; ++r) {
            int m = w * 32 + mi * 16 + lg * 4 + r;
            int R = blockIdx.x * 128 + m;
            int b = R / 169, tt = R - 169 * b;
            int ti = tt / 13, tj = tt - 13 * ti;
            #pragma unroll
            for (int ni = 0; ni < 5; ++ni) {
                int col = ni * 16 + lr;
                if (col < 75) {
                    float a = acc2[mi][ni][r] + b2S[col];
                    float o = 1.f / (1.f + expf(-a));
                    int c = col / 25, o25 = col - 25 * c;
                    int ph = o25 / 5, pw = o25 - 5 * ph;
                    int y = ti * 5 + ph, xx = tj * 5 + pw;
                    if (y < 64 && xx < 64)
                        img[(((size_t)b * 3 + c) * 64 + y) * 64 + xx] = o;
                }
            }
        }
}

// ======= split-K bf16 MFMA GEMM v7 (round-11 proven): counted-vmcnt pipe ====
// BM=256 x BN=128 x BK=64. 512 thr = 8 waves (4M x 2N), wave tile 64x64.
// LDS double-buffer, ONE raw s_barrier per K-step with manual lgkmcnt(0) only
// -> global loads stay IN FLIGHT across the barrier. W read exactly once.
// EPI=1: plain stores to partials C[z][256][N]. EPI=0: atomic into zeroed C.
template<int EPI>
__global__ __launch_bounds__(512, 2) void k_gemm_pipe(
    const unsigned short* __restrict__ A,
    const float* __restrict__ W,
    float* __restrict__ C,
    int N, int K, int baseSteps)
{
    __shared__ __align__(16) unsigned short As[2][256 * 64];  // 2 x 32 KB
    __shared__ __align__(16) unsigned short Ws[2][128 * 64];  // 2 x 16 KB

    int t = threadIdx.x;
    int bn = blockIdx.x * 128;
    int totalSteps = (K + 63) >> 6;
    int step0 = blockIdx.y * baseSteps;
    int nSteps = totalSteps - step0;
    if (nSteps > baseSteps) nSteps = baseSteps;
    if (nSteps <= 0) return;
    const bool nfull = (bn + 128 <= N);

    int w = t >> 6, lane = t & 63, lr = lane & 15, lg = lane >> 4;
    int wr = w >> 1, wc = w & 1;

    // A staging: row ar (0..255), half ah (0/32 ushorts), 4 x uint4
    int ar = t >> 1, ah = (t & 1) * 32;
    const unsigned short* Arow = A + (size_t)ar * K + ah;

    // W staging: col-quad nq (0..31) -> 4 cols; kb = 4*(t>>5): 4 contig k-rows
    int nq = t & 31, kb = (t >> 5) * 4;
    int nc = bn + 4 * nq;

    uint4  aP[4];
    float4 wP[4];

    f32x4 acc[4][4];
    #pragma unroll
    for (int i = 0; i < 4; ++i)
        #pragma unroll
        for (int j = 0; j < 4; ++j)
            acc[i][j] = (f32x4){0.f, 0.f, 0.f, 0.f};

    #define LOAD_T(stepIdx)                                                   \
    do {                                                                      \
        int kk0 = (stepIdx) << 6;                                             \
        if ((kk0 + 64 <= K) && nfull) {                                       \
            const uint4* ap = (const uint4*)(Arow + kk0);                     \
            _Pragma("unroll")                                                 \
            for (int u = 0; u < 4; ++u) aP[u] = ap[u];                        \
            const float* wp = W + (size_t)(kk0 + kb) * N + nc;                \
            _Pragma("unroll")                                                 \
            for (int jj = 0; jj < 4; ++jj)                                    \
                wP[jj] = *(const float4*)(wp + (size_t)jj * N);               \
        } else {                                                              \
            _Pragma("unroll")                                                 \
            for (int u = 0; u < 4; ++u) {                                     \
                int ak = kk0 + ah + u * 8;                                    \
                if (ak + 8 <= K) aP[u] = *(const uint4*)(Arow + kk0 + u * 8); \
                else             aP[u] = make_uint4(0, 0, 0, 0);              \
            }                                                                 \
            _Pragma("unroll")                                                 \
            for (int jj = 0; jj < 4; ++jj) {                                  \
                int kr = kk0 + kb + jj;                                       \
                float4 tmp = {0.f, 0.f, 0.f, 0.f};                            \
                if (kr < K) {                                                 \
                    const float* wp = W + (size_t)kr * N;                     \
                    if (nfull) tmp = *(const float4*)(wp + nc);               \
                    else {                                                    \
                        tmp.x = (nc + 0 < N) ? wp[nc + 0] : 0.f;              \
                        tmp.y = (nc + 1 < N) ? wp[nc + 1] : 0.f;              \
                        tmp.z = (nc + 2 < N) ? wp[nc + 2] : 0.f;              \
                        tmp.w = (nc + 3 < N) ? wp[nc + 3] : 0.f;              \
                    }                                                         \
                }                                                             \
                wP[jj] = tmp;                                                 \
            }                                                                 \
        }                                                                     \
    } while (0)

    #define STORE_T(buf)                                                      \
    do {                                                                      \
        _Pragma("unroll")                                                     \
        for (int u = 0; u < 4; ++u)                                           \
            *(uint4*)&As[buf][swe64(ar, ah + u * 8)] = aP[u];                 \
        _Pragma("unroll")                                                     \
        for (int c4 = 0; c4 < 4; ++c4) {                                      \
            int n = 4 * nq + c4;                                              \
            float e0 = (c4 == 0) ? wP[0].x : (c4 == 1) ? wP[0].y              \
                     : (c4 == 2) ? wP[0].z : wP[0].w;                         \
            float e1 = (c4 == 0) ? wP[1].x : (c4 == 1) ? wP[1].y              \
                     : (c4 == 2) ? wP[1].z : wP[1].w;                         \
            float e2 = (c4 == 0) ? wP[2].x : (c4 == 1) ? wP[2].y              \
                     : (c4 == 2) ? wP[2].z : wP[2].w;                         \
            float e3 = (c4 == 0) ? wP[3].x : (c4 == 1) ? wP[3].y              \
                     : (c4 == 2) ? wP[3].z : wP[3].w;                         \
            u16x4 pk;                                                         \
            pk.x = f2bf(e0); pk.y = f2bf(e1);                                 \
            pk.z = f2bf(e2); pk.w = f2bf(e3);                                 \
            *(u16x4*)&Ws[buf][swe64(n, kb)] = pk;                             \
        }                                                                     \
    } while (0)

    #define MFMA_T(buf)                                                       \
    do {                                                                      \
        _Pragma("unroll")                                                     \
        for (int kk = 0; kk < 64; kk += 32) {                                 \
            int kbase = kk + lg * 8;                                          \
            short8v afr[4], bfr[4];                                           \
            _Pragma("unroll")                                                 \
            for (int mi = 0; mi < 4; ++mi)                                    \
                afr[mi] = *(const short8v*)&As[buf][                          \
                    swe64(wr * 64 + mi * 16 + lr, kbase)];                    \
            _Pragma("unroll")                                                 \
            for (int ni = 0; ni < 4; ++ni)                                    \
                bfr[ni] = *(const short8v*)&Ws[buf][                          \
                    swe64(wc * 64 + ni * 16 + lr, kbase)];                    \
            _Pragma("unroll")                                                 \
            for (int mi = 0; mi < 4; ++mi)                                    \
                _Pragma("unroll")                                             \
                for (int ni = 0; ni < 4; ++ni)                                \
                    acc[mi][ni] = __builtin_amdgcn_mfma_f32_16x16x32_bf16(    \
                        afr[mi], bfr[ni], acc[mi][ni], 0, 0, 0);              \
        }                                                                     \
    } while (0)

    #define FENCE_BAR                                                         \
    do {                                                                      \
        asm volatile("s_waitcnt lgkmcnt(0)" ::: "memory");                    \
        __builtin_amdgcn_s_barrier();                                         \
        __builtin_amdgcn_sched_barrier(0);                                    \
    } while (0)

    // prologue: tile 0 -> buf 0; issue tile 1 loads (stay in flight)
    LOAD_T(step0);
    STORE_T(0);
    if (nSteps > 1) LOAD_T(step0 + 1);
    FENCE_BAR;

    int cur = 0;
    for (int ti = 0; ti < nSteps; ++ti) {
        if (ti + 1 < nSteps) {
            STORE_T(cur ^ 1);                      // regs = tile ti+1 (in flight 1 step)
            if (ti + 2 < nSteps) LOAD_T(step0 + ti + 2);  // fly across barrier
        }
        __builtin_amdgcn_s_setprio(1);
        MFMA_T(cur);
        __builtin_amdgcn_s_setprio(0);
        FENCE_BAR;
        cur ^= 1;
    }
    #undef LOAD_T
    #undef STORE_T
    #undef MFMA_T
    #undef FENCE_BAR

    if (EPI == 1) {
        float* Cz = C + (size_t)blockIdx.y * 256 * N;
        #pragma unroll
        for (int ni = 0; ni < 4; ++ni) {
            int col = bn + wc * 64 + ni * 16 + lr;
            if (col < N) {
                #pragma unroll
                for (int mi = 0; mi < 4; ++mi) {
                    int row = wr * 64 + mi * 16 + lg * 4;
                    #pragma unroll
                    for (int r = 0; r < 4; ++r)
                        Cz[(size_t)(row + r) * N + col] = acc[mi][ni][r];
                }
            }
        }
    } else {
        #pragma unroll
        for (int ni = 0; ni < 4; ++ni) {
            int col = bn + wc * 64 + ni * 16 + lr;
            if (col < N) {
                #pragma unroll
                for (int mi = 0; mi < 4; ++mi) {
                    int row = wr * 64 + mi * 16 + lg * 4;
                    #pragma unroll
                    for (int r = 0; r < 4; ++r)
                        __hip_atomic_fetch_add(&C[(size_t)(row + r) * N + col],
                                               acc[mi][ni][r],
                                               __ATOMIC_RELAXED,
                                               __HIP_MEMORY_SCOPE_AGENT);
                }
            }
        }
    }
}

// ---------- reduce partials + bias + relu (GEMM2 epilogue) ----------------
__global__ __launch_bounds__(256) void k_reduce_bias_relu(
    const float* __restrict__ parts, const float* __restrict__ bias,
    float* __restrict__ out, int S, int N)
{
    int nF4 = (256 / 4) * N;
    int nCol4 = N >> 2;
    size_t strideF4 = (size_t)64 * N;
    for (int idx = blockIdx.x * 256 + threadIdx.x; idx < nF4;
         idx += gridDim.x * 256) {
        int col4 = idx % nCol4;
        float4 b = *(const float4*)(bias + col4 * 4);
        float4 a = ((const float4*)parts)[idx];
        for (int z = 1; z < S; ++z) {
            float4 p = ((const float4*)parts)[(size_t)z * strideF4 + idx];
            a.x += p.x; a.y += p.y; a.z += p.z; a.w += p.w;
        }
        a.x = fmaxf(a.x + b.x, 0.f);
        a.y = fmaxf(a.y + b.y, 0.f);
        a.z = fmaxf(a.z + b.z, 0.f);
        a.w = fmaxf(a.w + b.w, 0.f);
        ((float4*)out)[idx] = a;
    }
}

// ---------- stats partial, FUSED with GEMM1 reduce+bias+relu ---------------
// hs[mm][kk] = relu(sum_z parts[z] + enc_b1); then psum = hs @ w2 chunk.
__global__ __launch_bounds__(256) void k_stats_partial(
    const float* __restrict__ parts,   // S x (256 x 4096) raw partials
    const float* __restrict__ enc_b1,
    const float* __restrict__ w2,
    float* __restrict__ psum,
    int S)
{
    __shared__ float hs[16][256];
    int mg = blockIdx.x >> 4;
    int ks = blockIdx.x & 15;
    int t = threadIdx.x;

    for (int i = t; i < 16 * 256; i += 256) {
        int mm = i >> 8, kk = i & 255;
        size_t off = (size_t)(mg * 16 + mm) * 4096 + ks * 256 + kk;
        float v = enc_b1[ks * 256 + kk];
        for (int z = 0; z < S; ++z)
            v += parts[(size_t)z * 1048576 + off];
        hs[mm][kk] = fmaxf(v, 0.f);
    }
    __syncthreads();

    int n = t & 127, mh = t >> 7;
    float acc[8] = {0.f,0.f,0.f,0.f,0.f,0.f,0.f,0.f};
    const float* w2p = w2 + (size_t)(ks * 256) * 128 + n;
    for (int k = 0; k < 256; ++k) {
        float wv = w2p[(size_t)k * 128];
        #pragma unroll
        for (int mm = 0; mm < 8; ++mm)
            acc[mm] += hs[mh * 8 + mm][k] * wv;
    }
    #pragma unroll
    for (int mm = 0; mm < 8; ++mm) {
        int m = mg * 16 + mh * 8 + mm;
        psum[((size_t)m * 16 + ks) * 128 + n] = acc[mm];
    }
}

// ---------- mid2 (unchanged) ----------
__global__ __launch_bounds__(256) void k_mid2(
    const float* __restrict__ psum,
    const float* __restrict__ enc_b2,
    const float* __restrict__ noise_z,
    const float* __restrict__ dec_w1, const float* __restrict__ dec_b1,
    const float* __restrict__ dec_w2, const float* __restrict__ dec_b2,
    float* __restrict__ mean_out, float* __restrict__ logvar_out,
    unsigned short* __restrict__ h2bf)
{
    __shared__ float st[128];
    __shared__ float z_s[64];
    __shared__ float h1_s[32];

    int m = blockIdx.x >> 2, ch = blockIdx.x & 3;
    int t = threadIdx.x;

    if (t < 128) {
        float a = enc_b2[t];
        #pragma unroll 4
        for (int ks = 0; ks < 16; ++ks)
            a += psum[((size_t)m * 16 + ks) * 128 + t];
        st[t] = fmaxf(a, 0.f);
    }
    __syncthreads();

    if (t < 64) {
        float mean = st[t], lv = st[t + 64];
        if (ch == 0) {
            mean_out[(size_t)m * 64 + t]   = mean;
            logvar_out[(size_t)m * 64 + t] = lv;
        }
        z_s[t] = noise_z[(size_t)m * 64 + t] * expf(0.5f * lv) + mean;
    }
    __syncthreads();

    if (t < 32) {
        float a = dec_b1[t];
        #pragma unroll 8
        for (int k = 0; k < 64; ++k) a += z_s[k] * dec_w1[k * 32 + t];
        h1_s[t] = fmaxf(a, 0.f);
    }
    __syncthreads();

    #pragma unroll
    for (int j = 0; j < 4; ++j) {
        int nn = ch * 1024 + j * 256 + t;
        float a = dec_b2[nn];
        #pragma unroll 8
        for (int k = 0; k < 32; ++k)
            a += h1_s[k] * dec_w2[(size_t)k * 4096 + nn];
        h2bf[(size_t)m * 4096 + nn] = f2bf(fmaxf(a, 0.f));
    }
}

extern "C" void kernel_launch(void* const* d_in, const int* in_sizes, int n_in,
                              void* d_out, int out_size, void* d_ws, size_t ws_size,
                              hipStream_t stream) {
    const float* x            = (const float*)d_in[0];
    const float* noise_little = (const float*)d_in[1];
    const float* noise_z      = (const float*)d_in[2];
    const float* le_w1        = (const float*)d_in[3];
    const float* le_b1        = (const float*)d_in[4];
    const float* le_w2        = (const float*)d_in[5];
    const float* le_b2        = (const float*)d_in[6];
    const float* ld_w1        = (const float*)d_in[7];
    const float* ld_b1        = (const float*)d_in[8];
    const float* ld_w2        = (const float*)d_in[9];
    const float* ld_b2        = (const float*)d_in[10];
    const float* enc_w1       = (const float*)d_in[11];
    const float* enc_b1       = (const float*)d_in[12];
    const float* enc_w2       = (const float*)d_in[13];
    const float* enc_b2       = (const float*)d_in[14];
    const float* dec_w1       = (const float*)d_in[15];
    const float* dec_b1       = (const float*)d_in[16];
    const float* dec_w2       = (const float*)d_in[17];
    const float* dec_b2       = (const float*)d_in[18];
    const float* dec_w3       = (const float*)d_in[19];
    const float* dec_b3       = (const float*)d_in[20];

    float* out = (float*)d_out;
    float* latent = out;                       // 1,806,336
    float* mean   = latent + 1806336;          // 16,384
    float* logvar = mean + 16384;              // 16,384
    float* nli    = logvar + 16384;            // 1,806,336
    float* img    = nli + 1806336;             // 3,145,728

    float* h_e = latent;   // fallback-only raw accumulator

    unsigned short* nli_bf = (unsigned short*)d_ws;                   // 3,612,672 B
    float* psum = (float*)((char*)d_ws + 3612672);                    // 2,097,152 B
    unsigned short* h2bf = (unsigned short*)((char*)d_ws + 5709824);  // 2,097,152 B
    float* parts = (float*)((char*)d_ws + 7806976);

    const size_t base = 7806976;
    const size_t slice1 = (size_t)256 * 4096 * 4;   // 4 MB
    const size_t slice2 = (size_t)256 * 7056 * 4;   // 7.2 MB
    const int S1 = (ws_size >= base + 8 * slice1) ? 8 : 0;
    const int S2 = (ws_size >= base + 8 * slice2) ? 8 : 0;

    // K-steps at BK=64: GEMM1 = 111, GEMM2 = 64. Grid x: 4096/128=32, 7056/128->56.

    // 1) patches + little_encode + reparam (MFMA)
    k_little_encode_mfma<<<882, 256, 0, stream>>>(
        x, noise_little, le_w1, le_b1, le_w2, le_b2, nli, nli_bf);

    // 2) GEMM1 partials [256x7056 @ 7056x4096]; W read once (BM=256)
    if (S1) {
        k_gemm_pipe<1><<<dim3(32, 8), 512, 0, stream>>>(
            nli_bf, enc_w1, parts, 4096, 7056, 14);
        // 3a) stats (fused reduce+bias+relu)
        k_stats_partial<<<256, 256, 0, stream>>>(parts, enc_b1, enc_w2, psum, 8);
    } else {
        hipMemsetAsync(h_e, 0, slice1, stream);
        k_gemm_pipe<0><<<dim3(32, 8), 512, 0, stream>>>(
            nli_bf, enc_w1, h_e, 4096, 7056, 14);
        k_stats_partial<<<256, 256, 0, stream>>>(h_e, enc_b1, enc_w2, psum, 1);
    }

    // 3b) reduce + reparam + dec1 + dec2
    k_mid2<<<1024, 256, 0, stream>>>(
        psum, enc_b2, noise_z, dec_w1, dec_b1, dec_w2, dec_b2,
        mean, logvar, h2bf);

    // 4) GEMM2 [256x4096 @ 4096x7056]; W read once
    if (S2) {
        k_gemm_pipe<1><<<dim3(56, 8), 512, 0, stream>>>(
            h2bf, dec_w3, parts, 7056, 4096, 8);
        k_reduce_bias_relu<<<1764, 256, 0, stream>>>(
            parts, dec_b3, latent, 8, 7056);
    } else {
        hipMemsetAsync(latent, 0, slice2, stream);
        k_gemm_pipe<0><<<dim3(56, 8), 512, 0, stream>>>(
            h2bf, dec_w3, latent, 7056, 4096, 8);
        k_reduce_bias_relu<<<1764, 256, 0, stream>>>(
            latent, dec_b3, latent, 1, 7056);
    }

    // 5) little_decode + canvas (MFMA)
    k_little_decode_mfma<<<338, 256, 0, stream>>>(
        latent, ld_w1, ld_b1, ld_w2, ld_b2, img);
}

// Round 14
// 202.741 us; speedup vs baseline: 1.1459x; 1.1100x over previous
//
#include <hip/hip_runtime.h>
#include <math.h>

#define EPSF 1e-6f

typedef __attribute__((ext_vector_type(8))) short short8v;
typedef __attribute__((ext_vector_type(4))) float f32x4;
typedef __attribute__((ext_vector_type(4))) unsigned short u16x4;

__device__ __forceinline__ unsigned short f2bf(float f) {
    union { float f; unsigned u; } v; v.f = f;
    return (unsigned short)((v.u + 0x7FFFu + ((v.u >> 16) & 1u)) >> 16);
}
// XOR swizzle for [row][128-ushort] LDS tiles (16B granularity)
__device__ __forceinline__ int swe(int row, int k) {
    return (row << 7) + (k ^ ((row & 7) << 3));
}
// XOR swizzle for [row][64-ushort] LDS tiles
__device__ __forceinline__ int swe64(int row, int k) {
    return (row << 6) + (k ^ ((row & 7) << 3));
}

// ================= little_encode via MFMA (unchanged, verified) =============
__global__ __launch_bounds__(256) void k_little_encode_mfma(
    const float* __restrict__ x,
    const float* __restrict__ noise,
    const float* __restrict__ w1,
    const float* __restrict__ b1,
    const float* __restrict__ w2,
    const float* __restrict__ b2,
    float* __restrict__ nli,
    unsigned short* __restrict__ nli_bf)
{
    __shared__ __align__(16) unsigned short pS[128 * 128];
    __shared__ __align__(16) unsigned short w1S[128 * 128];
    __shared__ __align__(16) unsigned short hS[128 * 128];
    __shared__ __align__(16) unsigned short w2S[32 * 128];
    __shared__ float b1S[128];
    __shared__ float b2S[32];
    __shared__ float sums[128][4];

    int t = threadIdx.x;

    {
        uint4 z4 = make_uint4(0, 0, 0, 0);
        #pragma unroll
        for (int i = 0; i < 8; ++i) {
            *(uint4*)&pS[(i * 256 + t) * 8]  = z4;
            *(uint4*)&w1S[(i * 256 + t) * 8] = z4;
        }
    }
    __syncthreads();

    for (int k = (t >> 4); k < 75; k += 16) {
        int n0 = (t & 15) * 8;
        float4 a0 = *(const float4*)(w1 + k * 128 + n0);
        float4 a1 = *(const float4*)(w1 + k * 128 + n0 + 4);
        w1S[swe(n0 + 0, k)] = f2bf(a0.x);
        w1S[swe(n0 + 1, k)] = f2bf(a0.y);
        w1S[swe(n0 + 2, k)] = f2bf(a0.z);
        w1S[swe(n0 + 3, k)] = f2bf(a0.w);
        w1S[swe(n0 + 4, k)] = f2bf(a1.x);
        w1S[swe(n0 + 5, k)] = f2bf(a1.y);
        w1S[swe(n0 + 6, k)] = f2bf(a1.z);
        w1S[swe(n0 + 7, k)] = f2bf(a1.w);
    }
    for (int k = (t >> 3); k < 128; k += 32) {
        int n0 = (t & 7) * 4;
        float4 a = *(const float4*)(w2 + k * 32 + n0);
        w2S[swe(n0 + 0, k)] = f2bf(a.x);
        w2S[swe(n0 + 1, k)] = f2bf(a.y);
        w2S[swe(n0 + 2, k)] = f2bf(a.z);
        w2S[swe(n0 + 3, k)] = f2bf(a.w);
    }
    if (t < 128) b1S[t] = b1[t];
    if (t < 32)  b2S[t] = b2[t];

    int row  = t & 127;
    int half = t >> 7;
    int R0 = blockIdx.x * 128 + row;
    int bb = R0 / 441;
    int p  = R0 - bb * 441;
    int pi = p / 21, pj = p - pi * 21;
    const float* xb = x + (size_t)bb * 3 * 63 * 63;

    float v[38];
    {
        float sA = 0.f, sB = 0.f;
        if (half == 0) {
            #pragma unroll
            for (int i = 0; i < 38; ++i) {
                const int k = i;
                const int c = k / 25, o = k % 25, ph = o / 5, pw = o % 5;
                int y = pi * 3 + ph - 1, xx = pj * 3 + pw - 1;
                float val = 0.f;
                if ((unsigned)y < 63u && (unsigned)xx < 63u)
                    val = xb[(c * 63 + y) * 63 + xx];
                v[i] = val;
                if (k < 25) sA += val; else sB += val;
            }
        } else {
            #pragma unroll
            for (int i = 0; i < 37; ++i) {
                const int k = 38 + i;
                const int c = k / 25, o = k % 25, ph = o / 5, pw = o % 5;
                int y = pi * 3 + ph - 1, xx = pj * 3 + pw - 1;
                float val = 0.f;
                if ((unsigned)y < 63u && (unsigned)xx < 63u)
                    val = xb[(c * 63 + y) * 63 + xx];
                v[i] = val;
                if (k < 50) sA += val; else sB += val;
            }
        }
        sums[row][half * 2 + 0] = sA;
        sums[row][half * 2 + 1] = sB;
    }
    __syncthreads();
    {
        float c0 = sums[row][0];
        float c1 = sums[row][1] + sums[row][2];
        float c2 = sums[row][3];
        if (half == 0) {
            #pragma unroll
            for (int i = 0; i < 38; ++i) {
                const int k = i;
                float cs = (k < 25) ? c0 : c1;
                pS[swe(row, k)] = f2bf(v[i] + EPSF * cs);
            }
        } else {
            #pragma unroll
            for (int i = 0; i < 37; ++i) {
                const int k = 38 + i;
                float cs = (k < 50) ? c1 : c2;
                pS[swe(row, k)] = f2bf(v[i] + EPSF * cs);
            }
        }
    }
    __syncthreads();

    int w = t >> 6, lane = t & 63, lr = lane & 15, lg = lane >> 4;

    f32x4 acc[2][8];
    #pragma unroll
    for (int mi = 0; mi < 2; ++mi)
        #pragma unroll
        for (int ni = 0; ni < 8; ++ni)
            acc[mi][ni] = (f32x4){0.f, 0.f, 0.f, 0.f};

    #pragma unroll
    for (int ks = 0; ks < 3; ++ks) {
        int kb = ks * 32 + lg * 8;
        short8v a0 = *(const short8v*)&pS[swe(w * 32 + lr, kb)];
        short8v a1 = *(const short8v*)&pS[swe(w * 32 + 16 + lr, kb)];
        #pragma unroll
        for (int ni = 0; ni < 8; ++ni) {
            short8v bf = *(const short8v*)&w1S[swe(ni * 16 + lr, kb)];
            acc[0][ni] = __builtin_amdgcn_mfma_f32_16x16x32_bf16(a0, bf, acc[0][ni], 0, 0, 0);
            acc[1][ni] = __builtin_amdgcn_mfma_f32_16x16x32_bf16(a1, bf, acc[1][ni], 0, 0, 0);
        }
    }
    #pragma unroll
    for (int mi = 0; mi < 2; ++mi)
        #pragma unroll
        for (int ni = 0; ni < 8; ++ni) {
            int n = ni * 16 + lr;
            float bv = b1S[n];
            #pragma unroll
            for (int r = 0; r < 4; ++r) {
                int m = w * 32 + mi * 16 + lg * 4 + r;
                hS[swe(m, n)] = f2bf(fmaxf(acc[mi][ni][r] + bv, 0.f));
            }
        }

    f32x4 acc2[2][2];
    #pragma unroll
    for (int mi = 0; mi < 2; ++mi)
        #pragma unroll
        for (int ni = 0; ni < 2; ++ni)
            acc2[mi][ni] = (f32x4){0.f, 0.f, 0.f, 0.f};

    #pragma unroll
    for (int kh = 0; kh < 4; ++kh) {
        int kb = kh * 32 + lg * 8;
        short8v a0 = *(const short8v*)&hS[swe(w * 32 + lr, kb)];
        short8v a1 = *(const short8v*)&hS[swe(w * 32 + 16 + lr, kb)];
        #pragma unroll
        for (int ni = 0; ni < 2; ++ni) {
            short8v bf = *(const short8v*)&w2S[swe(ni * 16 + lr, kb)];
            acc2[0][ni] = __builtin_amdgcn_mfma_f32_16x16x32_bf16(a0, bf, acc2[0][ni], 0, 0, 0);
            acc2[1][ni] = __builtin_amdgcn_mfma_f32_16x16x32_bf16(a1, bf, acc2[1][ni], 0, 0, 0);
        }
    }

    #pragma unroll
    for (int mi = 0; mi < 2; ++mi)
        #pragma unroll
        for (int r = 0; r < 4; ++r) {
            int m = w * 32 + mi * 16 + lg * 4 + r;
            size_t R = (size_t)blockIdx.x * 128 + m;
            float mean = acc2[mi][0][r] + b2S[lr];
            float lv   = acc2[mi][1][r] + b2S[16 + lr];
            float z = noise[R * 16 + lr] * expf(0.5f * lv) + mean;
            nli[R * 16 + lr] = z;
            nli_bf[R * 16 + lr] = f2bf(z);
        }
}

// ================= little_decode via MFMA (unchanged, verified) =============
__global__ __launch_bounds__(256) void k_little_decode_mfma(
    const float* __restrict__ latent,
    const float* __restrict__ w1,
    const float* __restrict__ b1,
    const float* __restrict__ w2,
    const float* __restrict__ b2,
    float* __restrict__ img)
{
    __shared__ __align__(16) unsigned short w1S[128 * 64];
    __shared__ __align__(16) unsigned short hS[128 * 128];
    __shared__ __align__(16) unsigned short w2S[80 * 128];
    __shared__ float b1S[128];
    __shared__ float b2S[80];

    int t = threadIdx.x;

    {
        uint4 z4 = make_uint4(0, 0, 0, 0);
        #pragma unroll
        for (int i = 0; i < 4; ++i)
            *(uint4*)&w1S[(i * 256 + t) * 8] = z4;
        #pragma unroll
        for (int i = 0; i < 5; ++i)
            *(uint4*)&w2S[(i * 256 + t) * 8] = z4;
    }
    __syncthreads();

    {
        int k = t >> 4;
        int n0 = (t & 15) * 8;
        float4 a0 = *(const float4*)(w1 + k * 128 + n0);
        float4 a1 = *(const float4*)(w1 + k * 128 + n0 + 4);
        w1S[swe64(n0 + 0, k)] = f2bf(a0.x);
        w1S[swe64(n0 + 1, k)] = f2bf(a0.y);
        w1S[swe64(n0 + 2, k)] = f2bf(a0.z);
        w1S[swe64(n0 + 3, k)] = f2bf(a0.w);
        w1S[swe64(n0 + 4, k)] = f2bf(a1.x);
        w1S[swe64(n0 + 5, k)] = f2bf(a1.y);
        w1S[swe64(n0 + 6, k)] = f2bf(a1.z);
        w1S[swe64(n0 + 7, k)] = f2bf(a1.w);
    }
    {
        int k = t >> 1;
        int half = t & 1;
        int n0 = half ? 38 : 0, n1 = half ? 75 : 38;
        for (int n = n0; n < n1; ++n)
            w2S[swe(n, k)] = f2bf(w2[k * 75 + n]);
    }
    if (t < 128) b1S[t] = b1[t];
    if (t < 80)  b2S[t] = (t < 75) ? b2[t] : 0.f;
    __syncthreads();

    int w = t >> 6, lane = t & 63, lr = lane & 15, lg = lane >> 4;

    f32x4 acc[2][8];
    #pragma unroll
    for (int mi = 0; mi < 2; ++mi)
        #pragma unroll
        for (int ni = 0; ni < 8; ++ni)
            acc[mi][ni] = (f32x4){0.f, 0.f, 0.f, 0.f};

    short8v af[2];
    #pragma unroll
    for (int mi = 0; mi < 2; ++mi) {
        int m = w * 32 + mi * 16 + lr;
        int R = blockIdx.x * 128 + m;
        int b = R / 169, tt = R - 169 * b;
        if (lg < 2) {
            const float* zp = latent + (size_t)b * 7056 + tt * 16 + lg * 8;
            float4 f0 = *(const float4*)(zp);
            float4 f1 = *(const float4*)(zp + 4);
            af[mi][0] = (short)f2bf(f0.x); af[mi][1] = (short)f2bf(f0.y);
            af[mi][2] = (short)f2bf(f0.z); af[mi][3] = (short)f2bf(f0.w);
            af[mi][4] = (short)f2bf(f1.x); af[mi][5] = (short)f2bf(f1.y);
            af[mi][6] = (short)f2bf(f1.z); af[mi][7] = (short)f2bf(f1.w);
        } else {
            af[mi] = (short8v){0,0,0,0,0,0,0,0};
        }
    }
    {
        int kb = lg * 8;
        #pragma unroll
        for (int ni = 0; ni < 8; ++ni) {
            short8v bf = *(const short8v*)&w1S[swe64(ni * 16 + lr, kb)];
            acc[0][ni] = __builtin_amdgcn_mfma_f32_16x16x32_bf16(af[0], bf, acc[0][ni], 0, 0, 0);
            acc[1][ni] = __builtin_amdgcn_mfma_f32_16x16x32_bf16(af[1], bf, acc[1][ni], 0, 0, 0);
        }
    }
    #pragma unroll
    for (int mi = 0; mi < 2; ++mi)
        #pragma unroll
        for (int ni = 0; ni < 8; ++ni) {
            int n = ni * 16 + lr;
            float bv = b1S[n];
            #pragma unroll
            for (int r = 0; r < 4; ++r) {
                int m = w * 32 + mi * 16 + lg * 4 + r;
                hS[swe(m, n)] = f2bf(fmaxf(acc[mi][ni][r] + bv, 0.f));
            }
        }

    f32x4 acc2[2][5];
    #pragma unroll
    for (int mi = 0; mi < 2; ++mi)
        #pragma unroll
        for (int ni = 0; ni < 5; ++ni)
            acc2[mi][ni] = (f32x4){0.f, 0.f, 0.f, 0.f};

    #pragma unroll
    for (int kh = 0; kh < 4; ++kh) {
        int kb = kh * 32 + lg * 8;
        short8v a0 = *(const short8v*)&hS[swe(w * 32 + lr, kb)];
        short8v a1 = *(const short8v*)&hS[swe(w * 32 + 16 + lr, kb)];
        #pragma unroll
        for (int ni = 0; ni < 5; ++ni) {
            short8v bf = *(const short8v*)&w2S[swe(ni * 16 + lr, kb)];
            acc2[0][ni] = __builtin_amdgcn_mfma_f32_16x16x32_bf16(a0, bf, acc2[0][ni], 0, 0, 0);
            acc2[1][ni] = __builtin_amdgcn_mfma_f32_16x16x32_bf16(a1, bf, acc2[1][ni], 0, 0, 0);
        }
    }

    #pragma unroll
    for (int mi = 0; mi < 2; ++mi)
        #pragma unroll
        for (int r = 0; r < 4; ++r) {
            int m = w * 32 + mi * 16 + lg * 4 + r;
            int R = blockIdx.x * 128 + m;
            int b = R / 169, tt = R - 169 * b;
            int ti = tt / 13, tj = tt - 13 * ti;
            #pragma unroll
            for (int ni = 0; ni < 5; ++ni) {
                int col = ni * 16 + lr;
                if (col < 75) {
                    float a = acc2[mi][ni][r] + b2S[col];
                    float o = 1.f / (1.f + expf(-a));
                    int c = col / 25, o25 = col - 25 * c;
                    int ph = o25 / 5, pw = o25 - 5 * ph;
                    int y = ti * 5 + ph, xx = tj * 5 + pw;
                    if (y < 64 && xx < 64)
                        img[(((size_t)b * 3 + c) * 64 + y) * 64 + xx] = o;
                }
            }
        }
}

// ======= split-K bf16 MFMA GEMM v9: depth-2 counted-vmcnt pipeline ==========
// BM=256 x BN=128 x BK=64. 512 thr = 8 waves (4M x 2N), wave tile 64x64.
// LDS dbuf 96 KB (1 block/CU -> VGPR budget 256: two static reg sets free).
// Loads stay in flight across TWO raw barriers (lgkmcnt-only fences).
// EPI=1: plain stores to partials C[z][256][N]. EPI=0: atomic into zeroed C.
template<int EPI>
__global__ __launch_bounds__(512, 2) void k_gemm_pipe(
    const unsigned short* __restrict__ A,
    const float* __restrict__ W,
    float* __restrict__ C,
    int N, int K, int baseSteps)
{
    __shared__ __align__(16) unsigned short As[2][256 * 64];  // 2 x 32 KB
    __shared__ __align__(16) unsigned short Ws[2][128 * 64];  // 2 x 16 KB

    int t = threadIdx.x;
    int bn = blockIdx.x * 128;
    int totalSteps = (K + 63) >> 6;
    int step0 = blockIdx.y * baseSteps;
    int nSteps = totalSteps - step0;
    if (nSteps > baseSteps) nSteps = baseSteps;
    if (nSteps <= 0) return;
    const bool nfull = (bn + 128 <= N);

    int w = t >> 6, lane = t & 63, lr = lane & 15, lg = lane >> 4;
    int wr = w >> 1, wc = w & 1;

    // A staging: row ar (0..255), half ah (0/32 ushorts), 4 x uint4
    int ar = t >> 1, ah = (t & 1) * 32;
    const unsigned short* Arow = A + (size_t)ar * K + ah;

    // W staging: col-quad nq (0..31) -> 4 cols; kb = 4*(t>>5): 4 contig k-rows
    int nq = t & 31, kb = (t >> 5) * 4;
    int nc = bn + 4 * nq;

    uint4  aPa[4], aPb[4];
    float4 wPa[4], wPb[4];

    f32x4 acc[4][4];
    #pragma unroll
    for (int i = 0; i < 4; ++i)
        #pragma unroll
        for (int j = 0; j < 4; ++j)
            acc[i][j] = (f32x4){0.f, 0.f, 0.f, 0.f};

    #define LOAD_T(AP, WP, stepIdx)                                           \
    do {                                                                      \
        int kk0 = (stepIdx) << 6;                                             \
        if ((kk0 + 64 <= K) && nfull) {                                       \
            const uint4* ap = (const uint4*)(Arow + kk0);                     \
            _Pragma("unroll")                                                 \
            for (int u = 0; u < 4; ++u) AP[u] = ap[u];                        \
            const float* wp = W + (size_t)(kk0 + kb) * N + nc;                \
            _Pragma("unroll")                                                 \
            for (int jj = 0; jj < 4; ++jj)                                    \
                WP[jj] = *(const float4*)(wp + (size_t)jj * N);               \
        } else {                                                              \
            _Pragma("unroll")                                                 \
            for (int u = 0; u < 4; ++u) {                                     \
                int ak = kk0 + ah + u * 8;                                    \
                if (ak + 8 <= K) AP[u] = *(const uint4*)(Arow + kk0 + u * 8); \
                else             AP[u] = make_uint4(0, 0, 0, 0);              \
            }                                                                 \
            _Pragma("unroll")                                                 \
            for (int jj = 0; jj < 4; ++jj) {                                  \
                int kr = kk0 + kb + jj;                                       \
                float4 tmp = {0.f, 0.f, 0.f, 0.f};                            \
                if (kr < K) {                                                 \
                    const float* wp = W + (size_t)kr * N;                     \
                    if (nfull) tmp = *(const float4*)(wp + nc);               \
                    else {                                                    \
                        tmp.x = (nc + 0 < N) ? wp[nc + 0] : 0.f;              \
                        tmp.y = (nc + 1 < N) ? wp[nc + 1] : 0.f;              \
                        tmp.z = (nc + 2 < N) ? wp[nc + 2] : 0.f;              \
                        tmp.w = (nc + 3 < N) ? wp[nc + 3] : 0.f;              \
                    }                                                         \
                }                                                             \
                WP[jj] = tmp;                                                 \
            }                                                                 \
        }                                                                     \
    } while (0)

    #define STORE_T(buf, AP, WP)                                              \
    do {                                                                      \
        _Pragma("unroll")                                                     \
        for (int u = 0; u < 4; ++u)                                           \
            *(uint4*)&As[buf][swe64(ar, ah + u * 8)] = AP[u];                 \
        _Pragma("unroll")                                                     \
        for (int c4 = 0; c4 < 4; ++c4) {                                      \
            int n = 4 * nq + c4;                                              \
            float e0 = (c4 == 0) ? WP[0].x : (c4 == 1) ? WP[0].y              \
                     : (c4 == 2) ? WP[0].z : WP[0].w;                         \
            float e1 = (c4 == 0) ? WP[1].x : (c4 == 1) ? WP[1].y              \
                     : (c4 == 2) ? WP[1].z : WP[1].w;                         \
            float e2 = (c4 == 0) ? WP[2].x : (c4 == 1) ? WP[2].y              \
                     : (c4 == 2) ? WP[2].z : WP[2].w;                         \
            float e3 = (c4 == 0) ? WP[3].x : (c4 == 1) ? WP[3].y              \
                     : (c4 == 2) ? WP[3].z : WP[3].w;                         \
            u16x4 pk;                                                         \
            pk.x = f2bf(e0); pk.y = f2bf(e1);                                 \
            pk.z = f2bf(e2); pk.w = f2bf(e3);                                 \
            *(u16x4*)&Ws[buf][swe64(n, kb)] = pk;                             \
        }                                                                     \
    } while (0)

    #define MFMA_T(buf)                                                       \
    do {                                                                      \
        _Pragma("unroll")                                                     \
        for (int kk = 0; kk < 64; kk += 32) {                                 \
            int kbase = kk + lg * 8;                                          \
            short8v afr[4], bfr[4];                                           \
            _Pragma("unroll")                                                 \
            for (int mi = 0; mi < 4; ++mi)                                    \
                afr[mi] = *(const short8v*)&As[buf][                          \
                    swe64(wr * 64 + mi * 16 + lr, kbase)];                    \
            _Pragma("unroll")                                                 \
            for (int ni = 0; ni < 4; ++ni)                                    \
                bfr[ni] = *(const short8v*)&Ws[buf][                          \
                    swe64(wc * 64 + ni * 16 + lr, kbase)];                    \
            _Pragma("unroll")                                                 \
            for (int mi = 0; mi < 4; ++mi)                                    \
                _Pragma("unroll")                                             \
                for (int ni = 0; ni < 4; ++ni)                                \
                    acc[mi][ni] = __builtin_amdgcn_mfma_f32_16x16x32_bf16(    \
                        afr[mi], bfr[ni], acc[mi][ni], 0, 0, 0);              \
        }                                                                     \
    } while (0)

    #define FENCE_BAR                                                         \
    do {                                                                      \
        asm volatile("s_waitcnt lgkmcnt(0)" ::: "memory");                    \
        __builtin_amdgcn_s_barrier();                                         \
        __builtin_amdgcn_sched_barrier(0);                                    \
    } while (0)

    // prologue: Sa=tile0 -> buf0; Sb=tile1 in flight; Sa refilled tile2
    LOAD_T(aPa, wPa, step0);
    if (nSteps > 1) LOAD_T(aPb, wPb, step0 + 1);
    STORE_T(0, aPa, wPa);
    if (nSteps > 2) LOAD_T(aPa, wPa, step0 + 2);
    FENCE_BAR;

    for (int ti = 0; ti < nSteps; ti += 2) {
        // even iter: compute buf0 (tile ti); stage tile ti+1 (Sb) -> buf1
        if (ti + 1 < nSteps) {
            STORE_T(1, aPb, wPb);                     // vmcnt waits Sb only
            if (ti + 3 < nSteps) LOAD_T(aPb, wPb, step0 + ti + 3);
        }
        __builtin_amdgcn_s_setprio(1);
        MFMA_T(0);
        __builtin_amdgcn_s_setprio(0);
        FENCE_BAR;
        if (ti + 1 >= nSteps) break;
        // odd iter: compute buf1 (tile ti+1); stage tile ti+2 (Sa) -> buf0
        if (ti + 2 < nSteps) {
            STORE_T(0, aPa, wPa);
            if (ti + 4 < nSteps) LOAD_T(aPa, wPa, step0 + ti + 4);
        }
        __builtin_amdgcn_s_setprio(1);
        MFMA_T(1);
        __builtin_amdgcn_s_setprio(0);
        FENCE_BAR;
    }
    #undef LOAD_T
    #undef STORE_T
    #undef MFMA_T
    #undef FENCE_BAR

    if (EPI == 1) {
        float* Cz = C + (size_t)blockIdx.y * 256 * N;
        #pragma unroll
        for (int ni = 0; ni < 4; ++ni) {
            int col = bn + wc * 64 + ni * 16 + lr;
            if (col < N) {
                #pragma unroll
                for (int mi = 0; mi < 4; ++mi) {
                    int row = wr * 64 + mi * 16 + lg * 4;
                    #pragma unroll
                    for (int r = 0; r < 4; ++r)
                        Cz[(size_t)(row + r) * N + col] = acc[mi][ni][r];
                }
            }
        }
    } else {
        #pragma unroll
        for (int ni = 0; ni < 4; ++ni) {
            int col = bn + wc * 64 + ni * 16 + lr;
            if (col < N) {
                #pragma unroll
                for (int mi = 0; mi < 4; ++mi) {
                    int row = wr * 64 + mi * 16 + lg * 4;
                    #pragma unroll
                    for (int r = 0; r < 4; ++r)
                        __hip_atomic_fetch_add(&C[(size_t)(row + r) * N + col],
                                               acc[mi][ni][r],
                                               __ATOMIC_RELAXED,
                                               __HIP_MEMORY_SCOPE_AGENT);
                }
            }
        }
    }
}

// ---------- reduce partials + bias + relu (also used S=1 in-place) ---------
__global__ __launch_bounds__(256) void k_reduce_bias_relu(
    const float* __restrict__ parts, const float* __restrict__ bias,
    float* __restrict__ out, int S, int N)
{
    int nF4 = (256 / 4) * N;
    int nCol4 = N >> 2;
    size_t strideF4 = (size_t)64 * N;
    for (int idx = blockIdx.x * 256 + threadIdx.x; idx < nF4;
         idx += gridDim.x * 256) {
        int col4 = idx % nCol4;
        float4 b = *(const float4*)(bias + col4 * 4);
        float4 a = ((const float4*)parts)[idx];
        for (int z = 1; z < S; ++z) {
            float4 p = ((const float4*)parts)[(size_t)z * strideF4 + idx];
            a.x += p.x; a.y += p.y; a.z += p.z; a.w += p.w;
        }
        a.x = fmaxf(a.x + b.x, 0.f);
        a.y = fmaxf(a.y + b.y, 0.f);
        a.z = fmaxf(a.z + b.z, 0.f);
        a.w = fmaxf(a.w + b.w, 0.f);
        ((float4*)out)[idx] = a;
    }
}

// ---------- stats partial (input h_e already bias+relu'd) ------------------
__global__ __launch_bounds__(256) void k_stats_partial(
    const float* __restrict__ h_e,
    const float* __restrict__ w2,
    float* __restrict__ psum)
{
    __shared__ float hs[16][256];
    int mg = blockIdx.x >> 4;
    int ks = blockIdx.x & 15;
    int t = threadIdx.x;

    for (int i = t; i < 16 * 256; i += 256) {
        int mm = i >> 8, kk = i & 255;
        hs[mm][kk] = h_e[(size_t)(mg * 16 + mm) * 4096 + ks * 256 + kk];
    }
    __syncthreads();

    int n = t & 127, mh = t >> 7;
    float acc[8] = {0.f,0.f,0.f,0.f,0.f,0.f,0.f,0.f};
    const float* w2p = w2 + (size_t)(ks * 256) * 128 + n;
    for (int k = 0; k < 256; ++k) {
        float wv = w2p[(size_t)k * 128];
        #pragma unroll
        for (int mm = 0; mm < 8; ++mm)
            acc[mm] += hs[mh * 8 + mm][k] * wv;
    }
    #pragma unroll
    for (int mm = 0; mm < 8; ++mm) {
        int m = mg * 16 + mh * 8 + mm;
        psum[((size_t)m * 16 + ks) * 128 + n] = acc[mm];
    }
}

// ---------- mid2 (unchanged) ----------
__global__ __launch_bounds__(256) void k_mid2(
    const float* __restrict__ psum,
    const float* __restrict__ enc_b2,
    const float* __restrict__ noise_z,
    const float* __restrict__ dec_w1, const float* __restrict__ dec_b1,
    const float* __restrict__ dec_w2, const float* __restrict__ dec_b2,
    float* __restrict__ mean_out, float* __restrict__ logvar_out,
    unsigned short* __restrict__ h2bf)
{
    __shared__ float st[128];
    __shared__ float z_s[64];
    __shared__ float h1_s[32];

    int m = blockIdx.x >> 2, ch = blockIdx.x & 3;
    int t = threadIdx.x;

    if (t < 128) {
        float a = enc_b2[t];
        #pragma unroll 4
        for (int ks = 0; ks < 16; ++ks)
            a += psum[((size_t)m * 16 + ks) * 128 + t];
        st[t] = fmaxf(a, 0.f);
    }
    __syncthreads();

    if (t < 64) {
        float mean = st[t], lv = st[t + 64];
        if (ch == 0) {
            mean_out[(size_t)m * 64 + t]   = mean;
            logvar_out[(size_t)m * 64 + t] = lv;
        }
        z_s[t] = noise_z[(size_t)m * 64 + t] * expf(0.5f * lv) + mean;
    }
    __syncthreads();

    if (t < 32) {
        float a = dec_b1[t];
        #pragma unroll 8
        for (int k = 0; k < 64; ++k) a += z_s[k] * dec_w1[k * 32 + t];
        h1_s[t] = fmaxf(a, 0.f);
    }
    __syncthreads();

    #pragma unroll
    for (int j = 0; j < 4; ++j) {
        int nn = ch * 1024 + j * 256 + t;
        float a = dec_b2[nn];
        #pragma unroll 8
        for (int k = 0; k < 32; ++k)
            a += h1_s[k] * dec_w2[(size_t)k * 4096 + nn];
        h2bf[(size_t)m * 4096 + nn] = f2bf(fmaxf(a, 0.f));
    }
}

extern "C" void kernel_launch(void* const* d_in, const int* in_sizes, int n_in,
                              void* d_out, int out_size, void* d_ws, size_t ws_size,
                              hipStream_t stream) {
    const float* x            = (const float*)d_in[0];
    const float* noise_little = (const float*)d_in[1];
    const float* noise_z      = (const float*)d_in[2];
    const float* le_w1        = (const float*)d_in[3];
    const float* le_b1        = (const float*)d_in[4];
    const float* le_w2        = (const float*)d_in[5];
    const float* le_b2        = (const float*)d_in[6];
    const float* ld_w1        = (const float*)d_in[7];
    const float* ld_b1        = (const float*)d_in[8];
    const float* ld_w2        = (const float*)d_in[9];
    const float* ld_b2        = (const float*)d_in[10];
    const float* enc_w1       = (const float*)d_in[11];
    const float* enc_b1       = (const float*)d_in[12];
    const float* enc_w2       = (const float*)d_in[13];
    const float* enc_b2       = (const float*)d_in[14];
    const float* dec_w1       = (const float*)d_in[15];
    const float* dec_b1       = (const float*)d_in[16];
    const float* dec_w2       = (const float*)d_in[17];
    const float* dec_b2       = (const float*)d_in[18];
    const float* dec_w3       = (const float*)d_in[19];
    const float* dec_b3       = (const float*)d_in[20];

    float* out = (float*)d_out;
    float* latent = out;                       // 1,806,336
    float* mean   = latent + 1806336;          // 16,384
    float* logvar = mean + 16384;              // 16,384
    float* nli    = logvar + 16384;            // 1,806,336
    float* img    = nli + 1806336;             // 3,145,728

    float* h_e = latent;   // bias+relu'd GEMM1 result parked here

    unsigned short* nli_bf = (unsigned short*)d_ws;                   // 3,612,672 B
    float* psum = (float*)((char*)d_ws + 3612672);                    // 2,097,152 B
    unsigned short* h2bf = (unsigned short*)((char*)d_ws + 5709824);  // 2,097,152 B
    float* parts = (float*)((char*)d_ws + 7806976);

    const size_t base = 7806976;
    const size_t slice1 = (size_t)256 * 4096 * 4;   // 4 MB
    const size_t slice2 = (size_t)256 * 7056 * 4;   // 7.2 MB
    const int S1 = (ws_size >= base + 8 * slice1) ? 8 : 0;
    const int S2 = (ws_size >= base + 8 * slice2) ? 8 : 0;

    // K-steps at BK=64: GEMM1 = 111, GEMM2 = 64. Grid x: 4096/128=32, 7056/128->56.

    // 1) patches + little_encode + reparam (MFMA)
    k_little_encode_mfma<<<882, 256, 0, stream>>>(
        x, noise_little, le_w1, le_b1, le_w2, le_b2, nli, nli_bf);

    // 2) GEMM1 [256x7056 @ 7056x4096]; W read once
    if (S1) {
        k_gemm_pipe<1><<<dim3(32, 8), 512, 0, stream>>>(
            nli_bf, enc_w1, parts, 4096, 7056, 14);
        k_reduce_bias_relu<<<1024, 256, 0, stream>>>(
            parts, enc_b1, h_e, 8, 4096);
    } else {
        hipMemsetAsync(h_e, 0, slice1, stream);
        k_gemm_pipe<0><<<dim3(32, 8), 512, 0, stream>>>(
            nli_bf, enc_w1, h_e, 4096, 7056, 14);
        k_reduce_bias_relu<<<1024, 256, 0, stream>>>(
            h_e, enc_b1, h_e, 1, 4096);
    }

    // 3) stats + reparam + dec1 + dec2
    k_stats_partial<<<256, 256, 0, stream>>>(h_e, enc_w2, psum);
    k_mid2<<<1024, 256, 0, stream>>>(
        psum, enc_b2, noise_z, dec_w1, dec_b1, dec_w2, dec_b2,
        mean, logvar, h2bf);

    // 4) GEMM2 [256x4096 @ 4096x7056]; W read once
    if (S2) {
        k_gemm_pipe<1><<<dim3(56, 8), 512, 0, stream>>>(
            h2bf, dec_w3, parts, 7056, 4096, 8);
        k_reduce_bias_relu<<<1764, 256, 0, stream>>>(
            parts, dec_b3, latent, 8, 7056);
    } else {
        hipMemsetAsync(latent, 0, slice2, stream);
        k_gemm_pipe<0><<<dim3(56, 8), 512, 0, stream>>>(
            h2bf, dec_w3, latent, 7056, 4096, 8);
        k_reduce_bias_relu<<<1764, 256, 0, stream>>>(
            latent, dec_b3, latent, 1, 7056);
    }

    // 5) little_decode + canvas (MFMA)
    k_little_decode_mfma<<<338, 256, 0, stream>>>(
        latent, ld_w1, ld_b1, ld_w2, ld_b2, img);
}

// Round 15
// 179.563 us; speedup vs baseline: 1.2938x; 1.1291x over previous
//
#include <hip/hip_runtime.h>
#include <math.h>

#define EPSF 1e-6f

typedef __attribute__((ext_vector_type(8))) short short8v;
typedef __attribute__((ext_vector_type(4))) float f32x4;
typedef __attribute__((ext_vector_type(4))) unsigned short u16x4;

__device__ __forceinline__ unsigned short f2bf(float f) {
    union { float f; unsigned u; } v; v.f = f;
    return (unsigned short)((v.u + 0x7FFFu + ((v.u >> 16) & 1u)) >> 16);
}
__device__ __forceinline__ float bf2f(unsigned short s) {
    union { unsigned u; float f; } v; v.u = ((unsigned)s) << 16;
    return v.f;
}
// XOR swizzle for [row][128-ushort] LDS tiles (16B granularity)
__device__ __forceinline__ int swe(int row, int k) {
    return (row << 7) + (k ^ ((row & 7) << 3));
}
// XOR swizzle for [row][64-ushort] LDS tiles
__device__ __forceinline__ int swe64(int row, int k) {
    return (row << 6) + (k ^ ((row & 7) << 3));
}

// ================= little_encode via MFMA (unchanged, verified) =============
__global__ __launch_bounds__(256) void k_little_encode_mfma(
    const float* __restrict__ x,
    const float* __restrict__ noise,
    const float* __restrict__ w1,
    const float* __restrict__ b1,
    const float* __restrict__ w2,
    const float* __restrict__ b2,
    float* __restrict__ nli,
    unsigned short* __restrict__ nli_bf)
{
    __shared__ __align__(16) unsigned short pS[128 * 128];
    __shared__ __align__(16) unsigned short w1S[128 * 128];
    __shared__ __align__(16) unsigned short hS[128 * 128];
    __shared__ __align__(16) unsigned short w2S[32 * 128];
    __shared__ float b1S[128];
    __shared__ float b2S[32];
    __shared__ float sums[128][4];

    int t = threadIdx.x;

    {
        uint4 z4 = make_uint4(0, 0, 0, 0);
        #pragma unroll
        for (int i = 0; i < 8; ++i) {
            *(uint4*)&pS[(i * 256 + t) * 8]  = z4;
            *(uint4*)&w1S[(i * 256 + t) * 8] = z4;
        }
    }
    __syncthreads();

    for (int k = (t >> 4); k < 75; k += 16) {
        int n0 = (t & 15) * 8;
        float4 a0 = *(const float4*)(w1 + k * 128 + n0);
        float4 a1 = *(const float4*)(w1 + k * 128 + n0 + 4);
        w1S[swe(n0 + 0, k)] = f2bf(a0.x);
        w1S[swe(n0 + 1, k)] = f2bf(a0.y);
        w1S[swe(n0 + 2, k)] = f2bf(a0.z);
        w1S[swe(n0 + 3, k)] = f2bf(a0.w);
        w1S[swe(n0 + 4, k)] = f2bf(a1.x);
        w1S[swe(n0 + 5, k)] = f2bf(a1.y);
        w1S[swe(n0 + 6, k)] = f2bf(a1.z);
        w1S[swe(n0 + 7, k)] = f2bf(a1.w);
    }
    for (int k = (t >> 3); k < 128; k += 32) {
        int n0 = (t & 7) * 4;
        float4 a = *(const float4*)(w2 + k * 32 + n0);
        w2S[swe(n0 + 0, k)] = f2bf(a.x);
        w2S[swe(n0 + 1, k)] = f2bf(a.y);
        w2S[swe(n0 + 2, k)] = f2bf(a.z);
        w2S[swe(n0 + 3, k)] = f2bf(a.w);
    }
    if (t < 128) b1S[t] = b1[t];
    if (t < 32)  b2S[t] = b2[t];

    int row  = t & 127;
    int half = t >> 7;
    int R0 = blockIdx.x * 128 + row;
    int bb = R0 / 441;
    int p  = R0 - bb * 441;
    int pi = p / 21, pj = p - pi * 21;
    const float* xb = x + (size_t)bb * 3 * 63 * 63;

    float v[38];
    {
        float sA = 0.f, sB = 0.f;
        if (half == 0) {
            #pragma unroll
            for (int i = 0; i < 38; ++i) {
                const int k = i;
                const int c = k / 25, o = k % 25, ph = o / 5, pw = o % 5;
                int y = pi * 3 + ph - 1, xx = pj * 3 + pw - 1;
                float val = 0.f;
                if ((unsigned)y < 63u && (unsigned)xx < 63u)
                    val = xb[(c * 63 + y) * 63 + xx];
                v[i] = val;
                if (k < 25) sA += val; else sB += val;
            }
        } else {
            #pragma unroll
            for (int i = 0; i < 37; ++i) {
                const int k = 38 + i;
                const int c = k / 25, o = k % 25, ph = o / 5, pw = o % 5;
                int y = pi * 3 + ph - 1, xx = pj * 3 + pw - 1;
                float val = 0.f;
                if ((unsigned)y < 63u && (unsigned)xx < 63u)
                    val = xb[(c * 63 + y) * 63 + xx];
                v[i] = val;
                if (k < 50) sA += val; else sB += val;
            }
        }
        sums[row][half * 2 + 0] = sA;
        sums[row][half * 2 + 1] = sB;
    }
    __syncthreads();
    {
        float c0 = sums[row][0];
        float c1 = sums[row][1] + sums[row][2];
        float c2 = sums[row][3];
        if (half == 0) {
            #pragma unroll
            for (int i = 0; i < 38; ++i) {
                const int k = i;
                float cs = (k < 25) ? c0 : c1;
                pS[swe(row, k)] = f2bf(v[i] + EPSF * cs);
            }
        } else {
            #pragma unroll
            for (int i = 0; i < 37; ++i) {
                const int k = 38 + i;
                float cs = (k < 50) ? c1 : c2;
                pS[swe(row, k)] = f2bf(v[i] + EPSF * cs);
            }
        }
    }
    __syncthreads();

    int w = t >> 6, lane = t & 63, lr = lane & 15, lg = lane >> 4;

    f32x4 acc[2][8];
    #pragma unroll
    for (int mi = 0; mi < 2; ++mi)
        #pragma unroll
        for (int ni = 0; ni < 8; ++ni)
            acc[mi][ni] = (f32x4){0.f, 0.f, 0.f, 0.f};

    #pragma unroll
    for (int ks = 0; ks < 3; ++ks) {
        int kb = ks * 32 + lg * 8;
        short8v a0 = *(const short8v*)&pS[swe(w * 32 + lr, kb)];
        short8v a1 = *(const short8v*)&pS[swe(w * 32 + 16 + lr, kb)];
        #pragma unroll
        for (int ni = 0; ni < 8; ++ni) {
            short8v bf = *(const short8v*)&w1S[swe(ni * 16 + lr, kb)];
            acc[0][ni] = __builtin_amdgcn_mfma_f32_16x16x32_bf16(a0, bf, acc[0][ni], 0, 0, 0);
            acc[1][ni] = __builtin_amdgcn_mfma_f32_16x16x32_bf16(a1, bf, acc[1][ni], 0, 0, 0);
        }
    }
    #pragma unroll
    for (int mi = 0; mi < 2; ++mi)
        #pragma unroll
        for (int ni = 0; ni < 8; ++ni) {
            int n = ni * 16 + lr;
            float bv = b1S[n];
            #pragma unroll
            for (int r = 0; r < 4; ++r) {
                int m = w * 32 + mi * 16 + lg * 4 + r;
                hS[swe(m, n)] = f2bf(fmaxf(acc[mi][ni][r] + bv, 0.f));
            }
        }

    f32x4 acc2[2][2];
    #pragma unroll
    for (int mi = 0; mi < 2; ++mi)
        #pragma unroll
        for (int ni = 0; ni < 2; ++ni)
            acc2[mi][ni] = (f32x4){0.f, 0.f, 0.f, 0.f};

    #pragma unroll
    for (int kh = 0; kh < 4; ++kh) {
        int kb = kh * 32 + lg * 8;
        short8v a0 = *(const short8v*)&hS[swe(w * 32 + lr, kb)];
        short8v a1 = *(const short8v*)&hS[swe(w * 32 + 16 + lr, kb)];
        #pragma unroll
        for (int ni = 0; ni < 2; ++ni) {
            short8v bf = *(const short8v*)&w2S[swe(ni * 16 + lr, kb)];
            acc2[0][ni] = __builtin_amdgcn_mfma_f32_16x16x32_bf16(a0, bf, acc2[0][ni], 0, 0, 0);
            acc2[1][ni] = __builtin_amdgcn_mfma_f32_16x16x32_bf16(a1, bf, acc2[1][ni], 0, 0, 0);
        }
    }

    #pragma unroll
    for (int mi = 0; mi < 2; ++mi)
        #pragma unroll
        for (int r = 0; r < 4; ++r) {
            int m = w * 32 + mi * 16 + lg * 4 + r;
            size_t R = (size_t)blockIdx.x * 128 + m;
            float mean = acc2[mi][0][r] + b2S[lr];
            float lv   = acc2[mi][1][r] + b2S[16 + lr];
            float z = noise[R * 16 + lr] * expf(0.5f * lv) + mean;
            nli[R * 16 + lr] = z;
            nli_bf[R * 16 + lr] = f2bf(z);
        }
}

// ================= little_decode via MFMA (unchanged, verified) =============
__global__ __launch_bounds__(256) void k_little_decode_mfma(
    const float* __restrict__ latent,
    const float* __restrict__ w1,
    const float* __restrict__ b1,
    const float* __restrict__ w2,
    const float* __restrict__ b2,
    float* __restrict__ img)
{
    __shared__ __align__(16) unsigned short w1S[128 * 64];
    __shared__ __align__(16) unsigned short hS[128 * 128];
    __shared__ __align__(16) unsigned short w2S[80 * 128];
    __shared__ float b1S[128];
    __shared__ float b2S[80];

    int t = threadIdx.x;

    {
        uint4 z4 = make_uint4(0, 0, 0, 0);
        #pragma unroll
        for (int i = 0; i < 4; ++i)
            *(uint4*)&w1S[(i * 256 + t) * 8] = z4;
        #pragma unroll
        for (int i = 0; i < 5; ++i)
            *(uint4*)&w2S[(i * 256 + t) * 8] = z4;
    }
    __syncthreads();

    {
        int k = t >> 4;
        int n0 = (t & 15) * 8;
        float4 a0 = *(const float4*)(w1 + k * 128 + n0);
        float4 a1 = *(const float4*)(w1 + k * 128 + n0 + 4);
        w1S[swe64(n0 + 0, k)] = f2bf(a0.x);
        w1S[swe64(n0 + 1, k)] = f2bf(a0.y);
        w1S[swe64(n0 + 2, k)] = f2bf(a0.z);
        w1S[swe64(n0 + 3, k)] = f2bf(a0.w);
        w1S[swe64(n0 + 4, k)] = f2bf(a1.x);
        w1S[swe64(n0 + 5, k)] = f2bf(a1.y);
        w1S[swe64(n0 + 6, k)] = f2bf(a1.z);
        w1S[swe64(n0 + 7, k)] = f2bf(a1.w);
    }
    {
        int k = t >> 1;
        int half = t & 1;
        int n0 = half ? 38 : 0, n1 = half ? 75 : 38;
        for (int n = n0; n < n1; ++n)
            w2S[swe(n, k)] = f2bf(w2[k * 75 + n]);
    }
    if (t < 128) b1S[t] = b1[t];
    if (t < 80)  b2S[t] = (t < 75) ? b2[t] : 0.f;
    __syncthreads();

    int w = t >> 6, lane = t & 63, lr = lane & 15, lg = lane >> 4;

    f32x4 acc[2][8];
    #pragma unroll
    for (int mi = 0; mi < 2; ++mi)
        #pragma unroll
        for (int ni = 0; ni < 8; ++ni)
            acc[mi][ni] = (f32x4){0.f, 0.f, 0.f, 0.f};

    short8v af[2];
    #pragma unroll
    for (int mi = 0; mi < 2; ++mi) {
        int m = w * 32 + mi * 16 + lr;
        int R = blockIdx.x * 128 + m;
        int b = R / 169, tt = R - 169 * b;
        if (lg < 2) {
            const float* zp = latent + (size_t)b * 7056 + tt * 16 + lg * 8;
            float4 f0 = *(const float4*)(zp);
            float4 f1 = *(const float4*)(zp + 4);
            af[mi][0] = (short)f2bf(f0.x); af[mi][1] = (short)f2bf(f0.y);
            af[mi][2] = (short)f2bf(f0.z); af[mi][3] = (short)f2bf(f0.w);
            af[mi][4] = (short)f2bf(f1.x); af[mi][5] = (short)f2bf(f1.y);
            af[mi][6] = (short)f2bf(f1.z); af[mi][7] = (short)f2bf(f1.w);
        } else {
            af[mi] = (short8v){0,0,0,0,0,0,0,0};
        }
    }
    {
        int kb = lg * 8;
        #pragma unroll
        for (int ni = 0; ni < 8; ++ni) {
            short8v bf = *(const short8v*)&w1S[swe64(ni * 16 + lr, kb)];
            acc[0][ni] = __builtin_amdgcn_mfma_f32_16x16x32_bf16(af[0], bf, acc[0][ni], 0, 0, 0);
            acc[1][ni] = __builtin_amdgcn_mfma_f32_16x16x32_bf16(af[1], bf, acc[1][ni], 0, 0, 0);
        }
    }
    #pragma unroll
    for (int mi = 0; mi < 2; ++mi)
        #pragma unroll
        for (int ni = 0; ni < 8; ++ni) {
            int n = ni * 16 + lr;
            float bv = b1S[n];
            #pragma unroll
            for (int r = 0; r < 4; ++r) {
                int m = w * 32 + mi * 16 + lg * 4 + r;
                hS[swe(m, n)] = f2bf(fmaxf(acc[mi][ni][r] + bv, 0.f));
            }
        }

    f32x4 acc2[2][5];
    #pragma unroll
    for (int mi = 0; mi < 2; ++mi)
        #pragma unroll
        for (int ni = 0; ni < 5; ++ni)
            acc2[mi][ni] = (f32x4){0.f, 0.f, 0.f, 0.f};

    #pragma unroll
    for (int kh = 0; kh < 4; ++kh) {
        int kb = kh * 32 + lg * 8;
        short8v a0 = *(const short8v*)&hS[swe(w * 32 + lr, kb)];
        short8v a1 = *(const short8v*)&hS[swe(w * 32 + 16 + lr, kb)];
        #pragma unroll
        for (int ni = 0; ni < 5; ++ni) {
            short8v bf = *(const short8v*)&w2S[swe(ni * 16 + lr, kb)];
            acc2[0][ni] = __builtin_amdgcn_mfma_f32_16x16x32_bf16(a0, bf, acc2[0][ni], 0, 0, 0);
            acc2[1][ni] = __builtin_amdgcn_mfma_f32_16x16x32_bf16(a1, bf, acc2[1][ni], 0, 0, 0);
        }
    }

    #pragma unroll
    for (int mi = 0; mi < 2; ++mi)
        #pragma unroll
        for (int r = 0; r < 4; ++r) {
            int m = w * 32 + mi * 16 + lg * 4 + r;
            int R = blockIdx.x * 128 + m;
            int b = R / 169, tt = R - 169 * b;
            int ti = tt / 13, tj = tt - 13 * ti;
            #pragma unroll
            for (int ni = 0; ni < 5; ++ni) {
                int col = ni * 16 + lr;
                if (col < 75) {
                    float a = acc2[mi][ni][r] + b2S[col];
                    float o = 1.f / (1.f + expf(-a));
                    int c = col / 25, o25 = col - 25 * c;
                    int ph = o25 / 5, pw = o25 - 5 * ph;
                    int y = ti * 5 + ph, xx = tj * 5 + pw;
                    if (y < 64 && xx < 64)
                        img[(((size_t)b * 3 + c) * 64 + y) * 64 + xx] = o;
                }
            }
        }
}

// ======= split-K bf16 MFMA GEMM (round-11 proven pipeline) ==================
// BM=256 x BN=128 x BK=64. 512 thr = 8 waves (4M x 2N), wave tile 64x64.
// LDS dbuf; ONE raw s_barrier per K-step with lgkmcnt(0)-only fence ->
// global loads stay in flight across the barrier. W read exactly once.
// EPI=1: bf16 stores to partials Cbf[z][256][N]. EPI=0: fp32 atomic into C.
template<int EPI>
__global__ __launch_bounds__(512, 2) void k_gemm_pipe(
    const unsigned short* __restrict__ A,
    const float* __restrict__ W,
    void* __restrict__ Cv,
    int N, int K, int baseSteps)
{
    __shared__ __align__(16) unsigned short As[2][256 * 64];  // 2 x 32 KB
    __shared__ __align__(16) unsigned short Ws[2][128 * 64];  // 2 x 16 KB

    int t = threadIdx.x;
    int bn = blockIdx.x * 128;
    int totalSteps = (K + 63) >> 6;
    int step0 = blockIdx.y * baseSteps;
    int nSteps = totalSteps - step0;
    if (nSteps > baseSteps) nSteps = baseSteps;
    if (nSteps <= 0) return;
    const bool nfull = (bn + 128 <= N);

    int w = t >> 6, lane = t & 63, lr = lane & 15, lg = lane >> 4;
    int wr = w >> 1, wc = w & 1;

    // A staging: row ar (0..255), half ah (0/32 ushorts), 4 x uint4
    int ar = t >> 1, ah = (t & 1) * 32;
    const unsigned short* Arow = A + (size_t)ar * K + ah;

    // W staging: col-quad nq (0..31) -> 4 cols; kb = 4*(t>>5): 4 contig k-rows
    int nq = t & 31, kb = (t >> 5) * 4;
    int nc = bn + 4 * nq;

    uint4  aP[4];
    float4 wP[4];

    f32x4 acc[4][4];
    #pragma unroll
    for (int i = 0; i < 4; ++i)
        #pragma unroll
        for (int j = 0; j < 4; ++j)
            acc[i][j] = (f32x4){0.f, 0.f, 0.f, 0.f};

    #define LOAD_T(stepIdx)                                                   \
    do {                                                                      \
        int kk0 = (stepIdx) << 6;                                             \
        if ((kk0 + 64 <= K) && nfull) {                                       \
            const uint4* ap = (const uint4*)(Arow + kk0);                     \
            _Pragma("unroll")                                                 \
            for (int u = 0; u < 4; ++u) aP[u] = ap[u];                        \
            const float* wp = W + (size_t)(kk0 + kb) * N + nc;                \
            _Pragma("unroll")                                                 \
            for (int jj = 0; jj < 4; ++jj)                                    \
                wP[jj] = *(const float4*)(wp + (size_t)jj * N);               \
        } else {                                                              \
            _Pragma("unroll")                                                 \
            for (int u = 0; u < 4; ++u) {                                     \
                int ak = kk0 + ah + u * 8;                                    \
                if (ak + 8 <= K) aP[u] = *(const uint4*)(Arow + kk0 + u * 8); \
                else             aP[u] = make_uint4(0, 0, 0, 0);              \
            }                                                                 \
            _Pragma("unroll")                                                 \
            for (int jj = 0; jj < 4; ++jj) {                                  \
                int kr = kk0 + kb + jj;                                       \
                float4 tmp = {0.f, 0.f, 0.f, 0.f};                            \
                if (kr < K) {                                                 \
                    const float* wp = W + (size_t)kr * N;                     \
                    if (nfull) tmp = *(const float4*)(wp + nc);               \
                    else {                                                    \
                        tmp.x = (nc + 0 < N) ? wp[nc + 0] : 0.f;              \
                        tmp.y = (nc + 1 < N) ? wp[nc + 1] : 0.f;              \
                        tmp.z = (nc + 2 < N) ? wp[nc + 2] : 0.f;              \
                        tmp.w = (nc + 3 < N) ? wp[nc + 3] : 0.f;              \
                    }                                                         \
                }                                                             \
                wP[jj] = tmp;                                                 \
            }                                                                 \
        }                                                                     \
    } while (0)

    #define STORE_T(buf)                                                      \
    do {                                                                      \
        _Pragma("unroll")                                                     \
        for (int u = 0; u < 4; ++u)                                           \
            *(uint4*)&As[buf][swe64(ar, ah + u * 8)] = aP[u];                 \
        _Pragma("unroll")                                                     \
        for (int c4 = 0; c4 < 4; ++c4) {                                      \
            int n = 4 * nq + c4;                                              \
            float e0 = (c4 == 0) ? wP[0].x : (c4 == 1) ? wP[0].y              \
                     : (c4 == 2) ? wP[0].z : wP[0].w;                         \
            float e1 = (c4 == 0) ? wP[1].x : (c4 == 1) ? wP[1].y              \
                     : (c4 == 2) ? wP[1].z : wP[1].w;                         \
            float e2 = (c4 == 0) ? wP[2].x : (c4 == 1) ? wP[2].y              \
                     : (c4 == 2) ? wP[2].z : wP[2].w;                         \
            float e3 = (c4 == 0) ? wP[3].x : (c4 == 1) ? wP[3].y              \
                     : (c4 == 2) ? wP[3].z : wP[3].w;                         \
            u16x4 pk;                                                         \
            pk.x = f2bf(e0); pk.y = f2bf(e1);                                 \
            pk.z = f2bf(e2); pk.w = f2bf(e3);                                 \
            *(u16x4*)&Ws[buf][swe64(n, kb)] = pk;                             \
        }                                                                     \
    } while (0)

    #define MFMA_T(buf)                                                       \
    do {                                                                      \
        _Pragma("unroll")                                                     \
        for (int kk = 0; kk < 64; kk += 32) {                                 \
            int kbase = kk + lg * 8;                                          \
            short8v afr[4], bfr[4];                                           \
            _Pragma("unroll")                                                 \
            for (int mi = 0; mi < 4; ++mi)                                    \
                afr[mi] = *(const short8v*)&As[buf][                          \
                    swe64(wr * 64 + mi * 16 + lr, kbase)];                    \
            _Pragma("unroll")                                                 \
            for (int ni = 0; ni < 4; ++ni)                                    \
                bfr[ni] = *(const short8v*)&Ws[buf][                          \
                    swe64(wc * 64 + ni * 16 + lr, kbase)];                    \
            _Pragma("unroll")                                                 \
            for (int mi = 0; mi < 4; ++mi)                                    \
                _Pragma("unroll")                                             \
                for (int ni = 0; ni < 4; ++ni)                                \
                    acc[mi][ni] = __builtin_amdgcn_mfma_f32_16x16x32_bf16(    \
                        afr[mi], bfr[ni], acc[mi][ni], 0, 0, 0);              \
        }                                                                     \
    } while (0)

    #define FENCE_BAR                                                         \
    do {                                                                      \
        asm volatile("s_waitcnt lgkmcnt(0)" ::: "memory");                    \
        __builtin_amdgcn_s_barrier();                                         \
        __builtin_amdgcn_sched_barrier(0);                                    \
    } while (0)

    // prologue: tile 0 -> buf 0; issue tile 1 loads (stay in flight)
    LOAD_T(step0);
    STORE_T(0);
    if (nSteps > 1) LOAD_T(step0 + 1);
    FENCE_BAR;

    int cur = 0;
    for (int ti = 0; ti < nSteps; ++ti) {
        if (ti + 1 < nSteps) {
            STORE_T(cur ^ 1);                      // regs = tile ti+1
            if (ti + 2 < nSteps) LOAD_T(step0 + ti + 2);  // fly across barrier
        }
        __builtin_amdgcn_s_setprio(1);
        MFMA_T(cur);
        __builtin_amdgcn_s_setprio(0);
        FENCE_BAR;
        cur ^= 1;
    }
    #undef LOAD_T
    #undef STORE_T
    #undef MFMA_T
    #undef FENCE_BAR

    if (EPI == 1) {
        unsigned short* Cz = (unsigned short*)Cv + (size_t)blockIdx.y * 256 * N;
        #pragma unroll
        for (int ni = 0; ni < 4; ++ni) {
            int col = bn + wc * 64 + ni * 16 + lr;
            if (col < N) {
                #pragma unroll
                for (int mi = 0; mi < 4; ++mi) {
                    int row = wr * 64 + mi * 16 + lg * 4;
                    #pragma unroll
                    for (int r = 0; r < 4; ++r)
                        Cz[(size_t)(row + r) * N + col] = f2bf(acc[mi][ni][r]);
                }
            }
        }
    } else {
        float* C = (float*)Cv;
        #pragma unroll
        for (int ni = 0; ni < 4; ++ni) {
            int col = bn + wc * 64 + ni * 16 + lr;
            if (col < N) {
                #pragma unroll
                for (int mi = 0; mi < 4; ++mi) {
                    int row = wr * 64 + mi * 16 + lg * 4;
                    #pragma unroll
                    for (int r = 0; r < 4; ++r)
                        __hip_atomic_fetch_add(&C[(size_t)(row + r) * N + col],
                                               acc[mi][ni][r],
                                               __ATOMIC_RELAXED,
                                               __HIP_MEMORY_SCOPE_AGENT);
                }
            }
        }
    }
}

// ---------- reduce bf16 partials + bias + relu -> fp32 out -----------------
// parts: S x [256][N] bf16. 8 elems/thread, grid-stride.
__global__ __launch_bounds__(256) void k_reduce_bf(
    const unsigned short* __restrict__ parts, const float* __restrict__ bias,
    float* __restrict__ out, int S, int N)
{
    int n8 = N >> 3;                        // 8-col groups per row
    int total = 256 * n8;
    size_t sliceE = (size_t)256 * N;        // ushort stride per z
    for (int idx = blockIdx.x * 256 + threadIdx.x; idx < total;
         idx += gridDim.x * 256) {
        int col8 = idx % n8;
        size_t e0 = (size_t)idx * 8;
        float s[8] = {0.f,0.f,0.f,0.f,0.f,0.f,0.f,0.f};
        for (int z = 0; z < S; ++z) {
            short8v p = *(const short8v*)(parts + (size_t)z * sliceE + e0);
            #pragma unroll
            for (int j = 0; j < 8; ++j)
                s[j] += bf2f((unsigned short)p[j]);
        }
        const float* bp = bias + col8 * 8;
        float4 o0, o1;
        o0.x = fmaxf(s[0] + bp[0], 0.f);
        o0.y = fmaxf(s[1] + bp[1], 0.f);
        o0.z = fmaxf(s[2] + bp[2], 0.f);
        o0.w = fmaxf(s[3] + bp[3], 0.f);
        o1.x = fmaxf(s[4] + bp[4], 0.f);
        o1.y = fmaxf(s[5] + bp[5], 0.f);
        o1.z = fmaxf(s[6] + bp[6], 0.f);
        o1.w = fmaxf(s[7] + bp[7], 0.f);
        *(float4*)(out + e0)     = o0;
        *(float4*)(out + e0 + 4) = o1;
    }
}

// ---------- fp32 in-place bias+relu (fallback path) ------------------------
__global__ __launch_bounds__(256) void k_reduce_bias_relu(
    const float* __restrict__ parts, const float* __restrict__ bias,
    float* __restrict__ out, int S, int N)
{
    int nF4 = (256 / 4) * N;
    int nCol4 = N >> 2;
    size_t strideF4 = (size_t)64 * N;
    for (int idx = blockIdx.x * 256 + threadIdx.x; idx < nF4;
         idx += gridDim.x * 256) {
        int col4 = idx % nCol4;
        float4 b = *(const float4*)(bias + col4 * 4);
        float4 a = ((const float4*)parts)[idx];
        for (int z = 1; z < S; ++z) {
            float4 p = ((const float4*)parts)[(size_t)z * strideF4 + idx];
            a.x += p.x; a.y += p.y; a.z += p.z; a.w += p.w;
        }
        a.x = fmaxf(a.x + b.x, 0.f);
        a.y = fmaxf(a.y + b.y, 0.f);
        a.z = fmaxf(a.z + b.z, 0.f);
        a.w = fmaxf(a.w + b.w, 0.f);
        ((float4*)out)[idx] = a;
    }
}

// ---------- stats partial (input h_e already bias+relu'd) ------------------
__global__ __launch_bounds__(256) void k_stats_partial(
    const float* __restrict__ h_e,
    const float* __restrict__ w2,
    float* __restrict__ psum)
{
    __shared__ float hs[16][256];
    int mg = blockIdx.x >> 4;
    int ks = blockIdx.x & 15;
    int t = threadIdx.x;

    for (int i = t; i < 16 * 256; i += 256) {
        int mm = i >> 8, kk = i & 255;
        hs[mm][kk] = h_e[(size_t)(mg * 16 + mm) * 4096 + ks * 256 + kk];
    }
    __syncthreads();

    int n = t & 127, mh = t >> 7;
    float acc[8] = {0.f,0.f,0.f,0.f,0.f,0.f,0.f,0.f};
    const float* w2p = w2 + (size_t)(ks * 256) * 128 + n;
    for (int k = 0; k < 256; ++k) {
        float wv = w2p[(size_t)k * 128];
        #pragma unroll
        for (int mm = 0; mm < 8; ++mm)
            acc[mm] += hs[mh * 8 + mm][k] * wv;
    }
    #pragma unroll
    for (int mm = 0; mm < 8; ++mm) {
        int m = mg * 16 + mh * 8 + mm;
        psum[((size_t)m * 16 + ks) * 128 + n] = acc[mm];
    }
}

// ---------- mid2 (unchanged) ----------
__global__ __launch_bounds__(256) void k_mid2(
    const float* __restrict__ psum,
    const float* __restrict__ enc_b2,
    const float* __restrict__ noise_z,
    const float* __restrict__ dec_w1, const float* __restrict__ dec_b1,
    const float* __restrict__ dec_w2, const float* __restrict__ dec_b2,
    float* __restrict__ mean_out, float* __restrict__ logvar_out,
    unsigned short* __restrict__ h2bf)
{
    __shared__ float st[128];
    __shared__ float z_s[64];
    __shared__ float h1_s[32];

    int m = blockIdx.x >> 2, ch = blockIdx.x & 3;
    int t = threadIdx.x;

    if (t < 128) {
        float a = enc_b2[t];
        #pragma unroll 4
        for (int ks = 0; ks < 16; ++ks)
            a += psum[((size_t)m * 16 + ks) * 128 + t];
        st[t] = fmaxf(a, 0.f);
    }
    __syncthreads();

    if (t < 64) {
        float mean = st[t], lv = st[t + 64];
        if (ch == 0) {
            mean_out[(size_t)m * 64 + t]   = mean;
            logvar_out[(size_t)m * 64 + t] = lv;
        }
        z_s[t] = noise_z[(size_t)m * 64 + t] * expf(0.5f * lv) + mean;
    }
    __syncthreads();

    if (t < 32) {
        float a = dec_b1[t];
        #pragma unroll 8
        for (int k = 0; k < 64; ++k) a += z_s[k] * dec_w1[k * 32 + t];
        h1_s[t] = fmaxf(a, 0.f);
    }
    __syncthreads();

    #pragma unroll
    for (int j = 0; j < 4; ++j) {
        int nn = ch * 1024 + j * 256 + t;
        float a = dec_b2[nn];
        #pragma unroll 8
        for (int k = 0; k < 32; ++k)
            a += h1_s[k] * dec_w2[(size_t)k * 4096 + nn];
        h2bf[(size_t)m * 4096 + nn] = f2bf(fmaxf(a, 0.f));
    }
}

extern "C" void kernel_launch(void* const* d_in, const int* in_sizes, int n_in,
                              void* d_out, int out_size, void* d_ws, size_t ws_size,
                              hipStream_t stream) {
    const float* x            = (const float*)d_in[0];
    const float* noise_little = (const float*)d_in[1];
    const float* noise_z      = (const float*)d_in[2];
    const float* le_w1        = (const float*)d_in[3];
    const float* le_b1        = (const float*)d_in[4];
    const float* le_w2        = (const float*)d_in[5];
    const float* le_b2        = (const float*)d_in[6];
    const float* ld_w1        = (const float*)d_in[7];
    const float* ld_b1        = (const float*)d_in[8];
    const float* ld_w2        = (const float*)d_in[9];
    const float* ld_b2        = (const float*)d_in[10];
    const float* enc_w1       = (const float*)d_in[11];
    const float* enc_b1       = (const float*)d_in[12];
    const float* enc_w2       = (const float*)d_in[13];
    const float* enc_b2       = (const float*)d_in[14];
    const float* dec_w1       = (const float*)d_in[15];
    const float* dec_b1       = (const float*)d_in[16];
    const float* dec_w2       = (const float*)d_in[17];
    const float* dec_b2       = (const float*)d_in[18];
    const float* dec_w3       = (const float*)d_in[19];
    const float* dec_b3       = (const float*)d_in[20];

    float* out = (float*)d_out;
    float* latent = out;                       // 1,806,336
    float* mean   = latent + 1806336;          // 16,384
    float* logvar = mean + 16384;              // 16,384
    float* nli    = logvar + 16384;            // 1,806,336
    float* img    = nli + 1806336;             // 3,145,728

    float* h_e = latent;   // bias+relu'd GEMM1 result parked here

    unsigned short* nli_bf = (unsigned short*)d_ws;                   // 3,612,672 B
    float* psum = (float*)((char*)d_ws + 3612672);                    // 2,097,152 B
    unsigned short* h2bf = (unsigned short*)((char*)d_ws + 5709824);  // 2,097,152 B
    unsigned short* partsBf = (unsigned short*)((char*)d_ws + 7806976);

    const size_t base = 7806976;
    // bf16 partials: GEMM1 8 x 256x4096x2 = 16.8 MB; GEMM2 4 x 256x7056x2 = 14.4 MB
    const bool wsPath = (ws_size >= base + (size_t)8 * 256 * 4096 * 2);

    // 1) patches + little_encode + reparam (MFMA)
    k_little_encode_mfma<<<882, 256, 0, stream>>>(
        x, noise_little, le_w1, le_b1, le_w2, le_b2, nli, nli_bf);

    // 2) GEMM1 [256x7056 @ 7056x4096]; K-steps 111, S=8 -> 256 blocks (1/CU)
    if (wsPath) {
        k_gemm_pipe<1><<<dim3(32, 8), 512, 0, stream>>>(
            nli_bf, enc_w1, partsBf, 4096, 7056, 14);
        k_reduce_bf<<<512, 256, 0, stream>>>(
            partsBf, enc_b1, h_e, 8, 4096);
    } else {
        hipMemsetAsync(h_e, 0, (size_t)256 * 4096 * 4, stream);
        k_gemm_pipe<0><<<dim3(32, 8), 512, 0, stream>>>(
            nli_bf, enc_w1, h_e, 4096, 7056, 14);
        k_reduce_bias_relu<<<1024, 256, 0, stream>>>(
            h_e, enc_b1, h_e, 1, 4096);
    }

    // 3) stats + reparam + dec1 + dec2
    k_stats_partial<<<256, 256, 0, stream>>>(h_e, enc_w2, psum);
    k_mid2<<<1024, 256, 0, stream>>>(
        psum, enc_b2, noise_z, dec_w1, dec_b1, dec_w2, dec_b2,
        mean, logvar, h2bf);

    // 4) GEMM2 [256x4096 @ 4096x7056]; K-steps 64, S=4 -> 224 blocks (1/CU)
    if (wsPath) {
        k_gemm_pipe<1><<<dim3(56, 4), 512, 0, stream>>>(
            h2bf, dec_w3, partsBf, 7056, 4096, 16);
        k_reduce_bf<<<882, 256, 0, stream>>>(
            partsBf, dec_b3, latent, 4, 7056);
    } else {
        hipMemsetAsync(latent, 0, (size_t)1806336 * 4, stream);
        k_gemm_pipe<0><<<dim3(56, 4), 512, 0, stream>>>(
            h2bf, dec_w3, latent, 7056, 4096, 16);
        k_reduce_bias_relu<<<1764, 256, 0, stream>>>(
            latent, dec_b3, latent, 1, 7056);
    }

    // 5) little_decode + canvas (MFMA)
    k_little_decode_mfma<<<338, 256, 0, stream>>>(
        latent, ld_w1, ld_b1, ld_w2, ld_b2, img);
}